// Round 1
// baseline (419.392 us; speedup 1.0000x reference)
//
#include <hip/hip_runtime.h>

typedef unsigned short u16;
typedef __attribute__((ext_vector_type(8))) short short8;
typedef __attribute__((ext_vector_type(4))) float f32x4;

// ---------- helpers ----------

__device__ __forceinline__ u16 f2bf(float f) {
  union { float f; unsigned u; } c; c.f = f;
  unsigned u = c.u;
  unsigned r = u + 0x7fffu + ((u >> 16) & 1u);
  return (u16)(r >> 16);
}

__device__ __forceinline__ void load_lds16(const void* g, void* l) {
  // dest: wave-uniform base + lane*16 (HW); src: per-lane global address
  __builtin_amdgcn_global_load_lds(
      (__attribute__((address_space(1))) void*)(__UINTPTR_TYPE__)(g),
      (__attribute__((address_space(3))) void*)(l),
      16, 0, 0);
}

// ---------- GEMM: C = A[M,K] @ Bt[N,K]^T  (bf16 in, fp32 accum) ----------
// MODE 0: bf16 out, C[row*ldc+col] = (acc + bias[col]) * scale
// MODE 1: bf16 out transposed, C[col*ldc+row] = (acc + bias[col]) * scale
// MODE 2: fp32 out, C[row*ldc+col] = acc
template <int MODE>
__global__ __launch_bounds__(256)
void gemm_bt(const u16* __restrict__ A, const u16* __restrict__ Bt,
             void* __restrict__ Cout, const float* __restrict__ bias,
             int K, int lda, int ldb, int ldc, float scale)
{
  __shared__ __align__(16) u16 smA[128 * 32];
  __shared__ __align__(16) u16 smB[128 * 32];

  const int t    = threadIdx.x;
  const int lane = t & 63;
  const int wave = t >> 6;
  const int wr   = wave >> 1;
  const int wc   = wave & 1;
  const long brow = (long)blockIdx.y * 128;
  const long bcol = (long)blockIdx.x * 128;

  f32x4 acc[4][4];
#pragma unroll
  for (int m = 0; m < 4; ++m)
#pragma unroll
    for (int n = 0; n < 4; ++n)
#pragma unroll
      for (int j = 0; j < 4; ++j)
        acc[m][n][j] = 0.f;

  // ---- staging geometry (per thread) ----
  // Linear LDS image of a 128x32 bf16 tile: row r = 64B. Thread t covers
  // bytes [i*4096 + t*16, +16). Swizzle: phys slot p holds logical slot
  // p ^ ((r>>1)&3)  (same for r and r+64 since bit 6 doesn't affect bits 1-2).
  const int L0  = t * 16;
  const int r0  = L0 >> 6;           // 0..63
  const int p0  = (L0 >> 4) & 3;
  const int sl0 = p0 ^ ((r0 >> 1) & 3);
  const int r1  = r0 + 64;

  const u16* gA0 = A  + (size_t)(brow + r0) * lda + sl0 * 8;
  const u16* gA1 = A  + (size_t)(brow + r1) * lda + sl0 * 8;
  const u16* gB0 = Bt + (size_t)(bcol + r0) * ldb + sl0 * 8;
  const u16* gB1 = Bt + (size_t)(bcol + r1) * ldb + sl0 * 8;

  const int fr = lane & 15;
  const int ks = lane >> 4;

  for (int kk = 0; kk < K; kk += 32) {
    load_lds16(gA0 + kk, &smA[wave * 512]);          // issue 0: rows 0..63
    load_lds16(gA1 + kk, &smA[2048 + wave * 512]);   // issue 1: rows 64..127
    load_lds16(gB0 + kk, &smB[wave * 512]);
    load_lds16(gB1 + kk, &smB[2048 + wave * 512]);
    __syncthreads();

    short8 af[4], bfr[4];
#pragma unroll
    for (int m = 0; m < 4; ++m) {
      const int rA = wr * 64 + m * 16 + fr;
      const int sl = ((rA >> 1) & 3) ^ ks;
      af[m] = *(const short8*)&smA[rA * 32 + sl * 8];
    }
#pragma unroll
    for (int n = 0; n < 4; ++n) {
      const int rB = wc * 64 + n * 16 + fr;
      const int sl = ((rB >> 1) & 3) ^ ks;
      bfr[n] = *(const short8*)&smB[rB * 32 + sl * 8];
    }
#pragma unroll
    for (int m = 0; m < 4; ++m)
#pragma unroll
      for (int n = 0; n < 4; ++n)
        acc[m][n] = __builtin_amdgcn_mfma_f32_16x16x32_bf16(af[m], bfr[n], acc[m][n], 0, 0, 0);
    __syncthreads();
  }

  // ---- epilogue ----
  const int dcol  = lane & 15;
  const int drow0 = (lane >> 4) * 4;
#pragma unroll
  for (int m = 0; m < 4; ++m) {
#pragma unroll
    for (int n = 0; n < 4; ++n) {
      const long col  = bcol + wc * 64 + n * 16 + dcol;
      const long rowb = brow + wr * 64 + m * 16 + drow0;
      float bv = 0.f;
      if (MODE != 2 && bias != nullptr) bv = bias[col];
#pragma unroll
      for (int j = 0; j < 4; ++j) {
        const long row = rowb + j;
        const float val = (acc[m][n][j] + bv) * scale;
        if (MODE == 0)      ((u16*)Cout)[(size_t)row * ldc + col] = f2bf(val);
        else if (MODE == 1) ((u16*)Cout)[(size_t)col * ldc + row] = f2bf(val);
        else                ((float*)Cout)[(size_t)row * ldc + col] = val;
      }
    }
  }
}

// ---------- fp32 -> bf16 convert (vectorized) ----------
__global__ __launch_bounds__(256)
void cvt_bf16(const float* __restrict__ in, u16* __restrict__ out, int n4)
{
  int i = blockIdx.x * 256 + threadIdx.x;
  const int stride = gridDim.x * 256;
  for (; i < n4; i += stride) {
    const float4 f = ((const float4*)in)[i];
    ushort4 u;
    u.x = f2bf(f.x); u.y = f2bf(f.y); u.z = f2bf(f.z); u.w = f2bf(f.w);
    ((ushort4*)out)[i] = u;
  }
}

// ---------- W[1024,1024] fp32 -> Wt[1024,1024] bf16 (transposed) ----------
__global__ __launch_bounds__(256)
void wtrans(const float* __restrict__ W, u16* __restrict__ Wt)
{
  __shared__ u16 tile[32][33];
  const int tx = threadIdx.x;      // 0..31
  const int ty = threadIdx.y;      // 0..7
  const int bx = blockIdx.x * 32;  // e base
  const int by = blockIdx.y * 32;  // d base
#pragma unroll
  for (int i = 0; i < 4; ++i)
    tile[ty + i * 8][tx] = f2bf(W[(size_t)(by + ty + i * 8) * 1024 + bx + tx]);
  __syncthreads();
#pragma unroll
  for (int i = 0; i < 4; ++i)
    Wt[(size_t)(bx + ty + i * 8) * 1024 + by + tx] = tile[tx][ty + i * 8];
}

// ---------- row softmax: S[2048,2048] fp32 -> P bf16 ----------
__global__ __launch_bounds__(256)
void softmax_rows(const float* __restrict__ S, u16* __restrict__ P)
{
  const int row = blockIdx.x;
  const float* s = S + (size_t)row * 2048;
  const int t = threadIdx.x;
  float v[8];
  float m = -1e30f;
#pragma unroll
  for (int i = 0; i < 8; ++i) { v[i] = s[t + i * 256]; m = fmaxf(m, v[i]); }
#pragma unroll
  for (int o = 32; o; o >>= 1) m = fmaxf(m, __shfl_xor(m, o));
  __shared__ float redm[4], reds[4];
  if ((t & 63) == 0) redm[t >> 6] = m;
  __syncthreads();
  m = fmaxf(fmaxf(redm[0], redm[1]), fmaxf(redm[2], redm[3]));
  float sum = 0.f;
#pragma unroll
  for (int i = 0; i < 8; ++i) { v[i] = __expf(v[i] - m); sum += v[i]; }
#pragma unroll
  for (int o = 32; o; o >>= 1) sum += __shfl_xor(sum, o);
  if ((t & 63) == 0) reds[t >> 6] = sum;
  __syncthreads();
  const float inv = 1.f / (reds[0] + reds[1] + reds[2] + reds[3]);
#pragma unroll
  for (int i = 0; i < 8; ++i)
    P[(size_t)row * 2048 + t + i * 256] = f2bf(v[i] * inv);
}

// ---------- launch ----------
extern "C" void kernel_launch(void* const* d_in, const int* in_sizes, int n_in,
                              void* d_out, int out_size, void* d_ws, size_t ws_size,
                              hipStream_t stream)
{
  const float* x  = (const float*)d_in[0];
  const float* bq = (const float*)d_in[2];
  const float* bk = (const float*)d_in[4];
  const float* bv = (const float*)d_in[6];
  const float* Wq = (const float*)d_in[1];
  const float* Wk = (const float*)d_in[3];
  const float* Wv = (const float*)d_in[5];
  float* out = (float*)d_out;
  char* ws = (char*)d_ws;

  const size_t MB = (size_t)1 << 20;
  u16*   xb  = (u16*)(ws);            // 16 MB: x as bf16 [8192][1024]
  u16*   Wqt = (u16*)(ws + 16 * MB);  // 2 MB: Wq^T bf16 [1024][1024]
  u16*   Wkt = (u16*)(ws + 18 * MB);
  u16*   Wvt = (u16*)(ws + 20 * MB);
  u16*   Qb  = (u16*)(ws + 22 * MB);  // 16 MB: (q+bq)/32 bf16 [8192][1024]
  u16*   Kb  = (u16*)(ws + 38 * MB);  // 16 MB
  u16*   Vt  = (u16*)(ws + 54 * MB);  // 16 MB: V^T bf16 [1024][8192]
  float* Sc  = (float*)(ws + 70 * MB);// 16 MB: scores fp32 [2048][2048] (1 batch)
  u16*   Pb  = (u16*)(ws + 86 * MB);  // 8 MB: weights bf16 [2048][2048] (1 batch)

  cvt_bf16<<<2048, 256, 0, stream>>>(x, xb, (4 * 2048 * 1024) / 4);
  {
    dim3 tb(32, 8), tg(32, 32);
    wtrans<<<tg, tb, 0, stream>>>(Wq, Wqt);
    wtrans<<<tg, tb, 0, stream>>>(Wk, Wkt);
    wtrans<<<tg, tb, 0, stream>>>(Wv, Wvt);
  }

  const float qscale = 0.03125f; // 1/sqrt(1024)
  // projections: M=8192, N=1024, K=1024
  gemm_bt<0><<<dim3(8, 64), 256, 0, stream>>>(xb, Wqt, Qb, bq, 1024, 1024, 1024, 1024, qscale);
  gemm_bt<0><<<dim3(8, 64), 256, 0, stream>>>(xb, Wkt, Kb, bk, 1024, 1024, 1024, 1024, 1.0f);
  gemm_bt<1><<<dim3(8, 64), 256, 0, stream>>>(xb, Wvt, Vt, bv, 1024, 1024, 1024, 8192, 1.0f);

  for (int b = 0; b < 4; ++b) {
    const size_t so = (size_t)b * 2048 * 1024;
    // scores = Q_b @ K_b^T : M=N=2048, K=1024 -> fp32
    gemm_bt<2><<<dim3(16, 16), 256, 0, stream>>>(Qb + so, Kb + so, Sc, nullptr,
                                                 1024, 1024, 1024, 2048, 1.0f);
    softmax_rows<<<2048, 256, 0, stream>>>(Sc, Pb);
    // out_b = P @ V_b : M=2048, N=1024, K=2048 (Bt = Vt[:, b*2048:], ldb=8192)
    gemm_bt<2><<<dim3(8, 16), 256, 0, stream>>>(Pb, Vt + (size_t)b * 2048, out + so, nullptr,
                                                2048, 2048, 8192, 1024, 1.0f);
  }
}

// Round 2
// 242.865 us; speedup vs baseline: 1.7269x; 1.7269x over previous
//
#include <hip/hip_runtime.h>

typedef unsigned short u16;
typedef __attribute__((ext_vector_type(8))) short short8;
typedef __attribute__((ext_vector_type(4))) float f32x4;

// ---------- helpers ----------

__device__ __forceinline__ u16 f2bf(float f) {
  union { float f; unsigned u; } c; c.f = f;
  unsigned u = c.u;
  unsigned r = u + 0x7fffu + ((u >> 16) & 1u);
  return (u16)(r >> 16);
}

__device__ __forceinline__ void load_lds16(const void* g, void* l) {
  // dest: wave-uniform base + lane*16 (HW); src: per-lane global address
  __builtin_amdgcn_global_load_lds(
      (__attribute__((address_space(1))) void*)(__UINTPTR_TYPE__)(g),
      (__attribute__((address_space(3))) void*)(l),
      16, 0, 0);
}

// ---------- GEMM: C = A[M,K] @ Bt[N,K]^T  (bf16 in, fp32 accum) ----------
// Double-buffered LDS, T3-minimal 2-phase schedule (prefetch next K-tile
// during MFMA of current; single counted-drain + raw barrier per K-step).
// MODE 0: bf16 out, C[row*ldc+col] = (acc + bias[col]) * scale
// MODE 1: bf16 out transposed, C[col*ldc+row] = (acc + bias[col]) * scale
// MODE 2: fp32 out, C[row*ldc+col] = acc
template <int MODE>
__global__ __launch_bounds__(256)
void gemm_bt(const u16* __restrict__ A, const u16* __restrict__ Bt,
             void* __restrict__ Cout, const float* __restrict__ bias,
             int K, int lda, int ldb, int ldc, float scale,
             long zsA, long zsB, long zsC)
{
  __shared__ __align__(16) u16 smA[2][128 * 32];
  __shared__ __align__(16) u16 smB[2][128 * 32];

  A  += (long)blockIdx.z * zsA;
  Bt += (long)blockIdx.z * zsB;

  const int t    = threadIdx.x;
  const int lane = t & 63;
  const int wave = t >> 6;
  const int wr   = wave >> 1;
  const int wc   = wave & 1;
  const long brow = (long)blockIdx.y * 128;
  const long bcol = (long)blockIdx.x * 128;

  f32x4 acc[4][4];
#pragma unroll
  for (int m = 0; m < 4; ++m)
#pragma unroll
    for (int n = 0; n < 4; ++n)
#pragma unroll
      for (int j = 0; j < 4; ++j)
        acc[m][n][j] = 0.f;

  // ---- staging geometry ----
  // Linear LDS image of a 128x32 bf16 tile: row r = 64B = 4 slots of 16B.
  // Phys slot p of row r holds logical slot p ^ ((r>>1)&3)  (both-sides
  // swizzle: pre-swizzled global source + swizzled ds_read).
  const int L0  = t * 16;
  const int r0  = L0 >> 6;           // 0..63
  const int p0  = (L0 >> 4) & 3;
  const int sl0 = p0 ^ ((r0 >> 1) & 3);
  const int r1  = r0 + 64;

  const u16* gA0 = A  + (size_t)(brow + r0) * lda + sl0 * 8;
  const u16* gA1 = A  + (size_t)(brow + r1) * lda + sl0 * 8;
  const u16* gB0 = Bt + (size_t)(bcol + r0) * ldb + sl0 * 8;
  const u16* gB1 = Bt + (size_t)(bcol + r1) * ldb + sl0 * 8;

  const int fr = lane & 15;
  const int ks = lane >> 4;

  // prologue: stage K-tile 0 into buffer 0
  load_lds16(gA0, &smA[0][wave * 512]);
  load_lds16(gA1, &smA[0][2048 + wave * 512]);
  load_lds16(gB0, &smB[0][wave * 512]);
  load_lds16(gB1, &smB[0][2048 + wave * 512]);
  asm volatile("s_waitcnt vmcnt(0)" ::: "memory");
  __builtin_amdgcn_s_barrier();

  int cur = 0;
  for (int kk = 0; kk < K; kk += 32) {
    const int nxt = cur ^ 1;
    if (kk + 32 < K) {  // issue next-tile loads; they fly during ds_read+MFMA
      load_lds16(gA0 + kk + 32, &smA[nxt][wave * 512]);
      load_lds16(gA1 + kk + 32, &smA[nxt][2048 + wave * 512]);
      load_lds16(gB0 + kk + 32, &smB[nxt][wave * 512]);
      load_lds16(gB1 + kk + 32, &smB[nxt][2048 + wave * 512]);
    }

    short8 af[4], bfr[4];
#pragma unroll
    for (int m = 0; m < 4; ++m) {
      const int rA = wr * 64 + m * 16 + fr;
      const int sl = ((rA >> 1) & 3) ^ ks;
      af[m] = *(const short8*)&smA[cur][rA * 32 + sl * 8];
    }
#pragma unroll
    for (int n = 0; n < 4; ++n) {
      const int rB = wc * 64 + n * 16 + fr;
      const int sl = ((rB >> 1) & 3) ^ ks;
      bfr[n] = *(const short8*)&smB[cur][rB * 32 + sl * 8];
    }
    // my LDS reads retired before the barrier (so next stage can't race them)
    asm volatile("s_waitcnt lgkmcnt(0)" ::: "memory");

#pragma unroll
    for (int m = 0; m < 4; ++m)
#pragma unroll
      for (int n = 0; n < 4; ++n)
        acc[m][n] = __builtin_amdgcn_mfma_f32_16x16x32_bf16(af[m], bfr[n], acc[m][n], 0, 0, 0);

    // next buffer fully staged + all waves done reading cur
    asm volatile("s_waitcnt vmcnt(0)" ::: "memory");
    __builtin_amdgcn_s_barrier();
    cur = nxt;
  }

  // ---- epilogue ----
  const int dcol  = lane & 15;
  const int drow0 = (lane >> 4) * 4;
#pragma unroll
  for (int m = 0; m < 4; ++m) {
#pragma unroll
    for (int n = 0; n < 4; ++n) {
      const long col  = bcol + wc * 64 + n * 16 + dcol;
      const long rowb = brow + wr * 64 + m * 16 + drow0;
      float bv = 0.f;
      if (MODE != 2 && bias != nullptr) bv = bias[col];
#pragma unroll
      for (int j = 0; j < 4; ++j) {
        const long row = rowb + j;
        const float val = (acc[m][n][j] + bv) * scale;
        if (MODE == 0)
          ((u16*)Cout)[(long)blockIdx.z * zsC + (size_t)row * ldc + col] = f2bf(val);
        else if (MODE == 1)
          ((u16*)Cout)[(long)blockIdx.z * zsC + (size_t)col * ldc + row] = f2bf(val);
        else
          ((float*)Cout)[(long)blockIdx.z * zsC + (size_t)row * ldc + col] = val;
      }
    }
  }
}

// ---------- fp32 -> bf16 convert (vectorized) ----------
__global__ __launch_bounds__(256)
void cvt_bf16(const float* __restrict__ in, u16* __restrict__ out, int n4)
{
  int i = blockIdx.x * 256 + threadIdx.x;
  const int stride = gridDim.x * 256;
  for (; i < n4; i += stride) {
    const float4 f = ((const float4*)in)[i];
    ushort4 u;
    u.x = f2bf(f.x); u.y = f2bf(f.y); u.z = f2bf(f.z); u.w = f2bf(f.w);
    ((ushort4*)out)[i] = u;
  }
}

// ---------- W[1024,1024] fp32 -> Wt[1024,1024] bf16 (transposed) ----------
__global__ __launch_bounds__(256)
void wtrans(const float* __restrict__ W, u16* __restrict__ Wt)
{
  __shared__ u16 tile[32][33];
  const int tx = threadIdx.x;      // 0..31
  const int ty = threadIdx.y;      // 0..7
  const int bx = blockIdx.x * 32;  // e base
  const int by = blockIdx.y * 32;  // d base
#pragma unroll
  for (int i = 0; i < 4; ++i)
    tile[ty + i * 8][tx] = f2bf(W[(size_t)(by + ty + i * 8) * 1024 + bx + tx]);
  __syncthreads();
#pragma unroll
  for (int i = 0; i < 4; ++i)
    Wt[(size_t)(bx + ty + i * 8) * 1024 + by + tx] = tile[tx][ty + i * 8];
}

// ---------- row softmax, IN-PLACE: S fp32 [nb][2048][2048] -> P bf16 ----------
// P row b,r occupies the first 4KB of the fp32 row (u16 lda = 4096).
__global__ __launch_bounds__(256)
void softmax_rows(float* __restrict__ S)
{
  const long row   = blockIdx.x;
  const long batch = row >> 11;
  float* s = S + batch * (2048L * 2048) + (row & 2047) * 2048L;
  const int t = threadIdx.x;

  const float4 f0 = ((const float4*)s)[t];
  const float4 f1 = ((const float4*)s)[t + 256];
  float vals[8] = {f0.x, f0.y, f0.z, f0.w, f1.x, f1.y, f1.z, f1.w};

  float m = -1e30f;
#pragma unroll
  for (int i = 0; i < 8; ++i) m = fmaxf(m, vals[i]);
#pragma unroll
  for (int o = 32; o; o >>= 1) m = fmaxf(m, __shfl_xor(m, o));
  __shared__ float redm[4], reds[4];
  if ((t & 63) == 0) redm[t >> 6] = m;
  __syncthreads();   // also separates in-place reads from writes
  m = fmaxf(fmaxf(redm[0], redm[1]), fmaxf(redm[2], redm[3]));

  float sum = 0.f;
#pragma unroll
  for (int i = 0; i < 8; ++i) { vals[i] = __expf(vals[i] - m); sum += vals[i]; }
#pragma unroll
  for (int o = 32; o; o >>= 1) sum += __shfl_xor(sum, o);
  if ((t & 63) == 0) reds[t >> 6] = sum;
  __syncthreads();
  const float inv = 1.f / (reds[0] + reds[1] + reds[2] + reds[3]);

  u16* p = (u16*)s;
  ushort4 o0, o1;
  o0.x = f2bf(vals[0] * inv); o0.y = f2bf(vals[1] * inv);
  o0.z = f2bf(vals[2] * inv); o0.w = f2bf(vals[3] * inv);
  o1.x = f2bf(vals[4] * inv); o1.y = f2bf(vals[5] * inv);
  o1.z = f2bf(vals[6] * inv); o1.w = f2bf(vals[7] * inv);
  ((ushort4*)p)[t] = o0;
  ((ushort4*)p)[t + 256] = o1;
}

// ---------- launch ----------
extern "C" void kernel_launch(void* const* d_in, const int* in_sizes, int n_in,
                              void* d_out, int out_size, void* d_ws, size_t ws_size,
                              hipStream_t stream)
{
  const float* x  = (const float*)d_in[0];
  const float* Wq = (const float*)d_in[1];
  const float* bq = (const float*)d_in[2];
  const float* Wk = (const float*)d_in[3];
  const float* bk = (const float*)d_in[4];
  const float* Wv = (const float*)d_in[5];
  const float* bv = (const float*)d_in[6];
  float* out = (float*)d_out;
  char* ws = (char*)d_ws;

  const size_t MB = (size_t)1 << 20;
  const float qscale = 0.03125f;  // 1/sqrt(1024)
  const long  SO = 2048L * 1024;  // per-batch Q/K/out element stride

  if (ws_size >= 112 * MB) {
    // ---- batched path (112 MB) ----
    u16*   Qb  = (u16*)(ws);             // 16 MB  [8192][1024] bf16, pre-scaled
    u16*   Kb  = (u16*)(ws + 16 * MB);   // 16 MB
    u16*   Vt  = (u16*)(ws + 32 * MB);   // 16 MB  V^T [1024][8192] bf16
    float* Sc  = (float*)(ws + 48 * MB); // 64 MB  scores fp32 [4][2048][2048] (P in-place)
    u16*   xb  = (u16*)(ws + 48 * MB);   // 16 MB  (overlaps Sc; dead before scores)
    u16*   Wqt = (u16*)(ws + 64 * MB);   // 2 MB   (overlaps Sc; dead before scores)
    u16*   Wkt = (u16*)(ws + 66 * MB);
    u16*   Wvt = (u16*)(ws + 68 * MB);

    cvt_bf16<<<2048, 256, 0, stream>>>(x, xb, (4 * 2048 * 1024) / 4);
    dim3 tb(32, 8), tg(32, 32);
    wtrans<<<tg, tb, 0, stream>>>(Wq, Wqt);
    wtrans<<<tg, tb, 0, stream>>>(Wk, Wkt);
    wtrans<<<tg, tb, 0, stream>>>(Wv, Wvt);

    gemm_bt<0><<<dim3(8, 64), 256, 0, stream>>>(xb, Wqt, Qb, bq, 1024, 1024, 1024, 1024, qscale, 0, 0, 0);
    gemm_bt<0><<<dim3(8, 64), 256, 0, stream>>>(xb, Wkt, Kb, bk, 1024, 1024, 1024, 1024, 1.0f, 0, 0, 0);
    gemm_bt<1><<<dim3(8, 64), 256, 0, stream>>>(xb, Wvt, Vt, bv, 1024, 1024, 1024, 8192, 1.0f, 0, 0, 0);

    // scores (all batches): [2048,2048] = Q_b @ K_b^T
    gemm_bt<2><<<dim3(16, 16, 4), 256, 0, stream>>>(Qb, Kb, Sc, nullptr,
        1024, 1024, 1024, 2048, 1.0f, SO, SO, 2048L * 2048);
    softmax_rows<<<4 * 2048, 256, 0, stream>>>(Sc);
    // out (all batches): P_b @ V_b  (P in-place in Sc, u16 lda=4096)
    gemm_bt<2><<<dim3(8, 16, 4), 256, 0, stream>>>((const u16*)Sc, Vt, out, nullptr,
        2048, 4096, 8192, 1024, 1.0f, 2048L * 4096, 2048, SO);
  } else {
    // ---- per-batch fallback (86 MB) ----
    u16*   xb  = (u16*)(ws);             // 16 MB
    u16*   Wqt = (u16*)(ws + 16 * MB);
    u16*   Wkt = (u16*)(ws + 18 * MB);
    u16*   Wvt = (u16*)(ws + 20 * MB);
    u16*   Qb  = (u16*)(ws + 22 * MB);   // 16 MB
    u16*   Kb  = (u16*)(ws + 38 * MB);   // 16 MB
    u16*   Vt  = (u16*)(ws + 54 * MB);   // 16 MB
    float* Sc  = (float*)(ws + 70 * MB); // 16 MB (1 batch; P in-place)

    cvt_bf16<<<2048, 256, 0, stream>>>(x, xb, (4 * 2048 * 1024) / 4);
    dim3 tb(32, 8), tg(32, 32);
    wtrans<<<tg, tb, 0, stream>>>(Wq, Wqt);
    wtrans<<<tg, tb, 0, stream>>>(Wk, Wkt);
    wtrans<<<tg, tb, 0, stream>>>(Wv, Wvt);

    gemm_bt<0><<<dim3(8, 64), 256, 0, stream>>>(xb, Wqt, Qb, bq, 1024, 1024, 1024, 1024, qscale, 0, 0, 0);
    gemm_bt<0><<<dim3(8, 64), 256, 0, stream>>>(xb, Wkt, Kb, bk, 1024, 1024, 1024, 1024, 1.0f, 0, 0, 0);
    gemm_bt<1><<<dim3(8, 64), 256, 0, stream>>>(xb, Wvt, Vt, bv, 1024, 1024, 1024, 8192, 1.0f, 0, 0, 0);

    for (int b = 0; b < 4; ++b) {
      gemm_bt<2><<<dim3(16, 16), 256, 0, stream>>>(Qb + b * SO, Kb + b * SO, Sc, nullptr,
          1024, 1024, 1024, 2048, 1.0f, 0, 0, 0);
      softmax_rows<<<2048, 256, 0, stream>>>(Sc);
      gemm_bt<2><<<dim3(8, 16), 256, 0, stream>>>((const u16*)Sc, Vt + 2048L * b, out + b * SO, nullptr,
          2048, 4096, 8192, 1024, 1.0f, 0, 0, 0);
    }
  }
}

// Round 3
// 215.086 us; speedup vs baseline: 1.9499x; 1.1292x over previous
//
#include <hip/hip_runtime.h>

typedef unsigned short u16;
typedef __attribute__((ext_vector_type(8))) short short8;
typedef __attribute__((ext_vector_type(4))) float f32x4;

// ---------- helpers ----------

__device__ __forceinline__ u16 f2bf(float f) {
  union { float f; unsigned u; } c; c.f = f;
  unsigned u = c.u;
  unsigned r = u + 0x7fffu + ((u >> 16) & 1u);
  return (u16)(r >> 16);
}

__device__ __forceinline__ float bf2f(u16 b) {
  union { unsigned u; float f; } c; c.u = ((unsigned)b) << 16;
  return c.f;
}

__device__ __forceinline__ void load_lds16(const void* g, void* l) {
  // dest: wave-uniform base + lane*16 (HW); src: per-lane global address
  __builtin_amdgcn_global_load_lds(
      (__attribute__((address_space(1))) void*)(__UINTPTR_TYPE__)(g),
      (__attribute__((address_space(3))) void*)(l),
      16, 0, 0);
}

// ---------- GEMM: C = A[M,K] @ Bt[N,K]^T  (bf16 in, fp32 accum) ----------
// Depth-2 software pipeline (3 K-tiles in flight, counted vmcnt(4), raw
// barriers, no full drain in the main loop).
// MODE 0: bf16 out, C[row*ldc+col] = (acc + bias[col]) * scale
// MODE 1: bf16 out transposed, C[col*ldc+row] = (acc + bias[col]) * scale
// MODE 2: fp32 out, C[row*ldc+col] = acc
template <int MODE>
__global__ __launch_bounds__(256)
void gemm_bt(const u16* __restrict__ A, const u16* __restrict__ Bt,
             void* __restrict__ Cout, const float* __restrict__ bias,
             int K, int lda, int ldb, int ldc, float scale,
             long zsA, long zsB, long zsC)
{
  __shared__ __align__(16) u16 smA[2][128 * 32];
  __shared__ __align__(16) u16 smB[2][128 * 32];

  A  += (long)blockIdx.z * zsA;
  Bt += (long)blockIdx.z * zsB;

  const int t    = threadIdx.x;
  const int lane = t & 63;
  const int wave = t >> 6;
  const int wr   = wave >> 1;
  const int wc   = wave & 1;
  const long brow = (long)blockIdx.y * 128;
  const long bcol = (long)blockIdx.x * 128;

  f32x4 acc[4][4];
#pragma unroll
  for (int m = 0; m < 4; ++m)
#pragma unroll
    for (int n = 0; n < 4; ++n)
#pragma unroll
      for (int j = 0; j < 4; ++j)
        acc[m][n][j] = 0.f;

  // ---- staging geometry ----
  // Linear LDS image of a 128x32 bf16 tile: row r = 64B = 4 slots of 16B.
  // Phys slot p of row r holds logical slot p ^ ((r>>1)&3)  (both-sides
  // swizzle: pre-swizzled global source + swizzled ds_read).
  const int L0  = t * 16;
  const int r0  = L0 >> 6;           // 0..63
  const int p0  = (L0 >> 4) & 3;
  const int sl0 = p0 ^ ((r0 >> 1) & 3);
  const int r1  = r0 + 64;

  const u16* gA0 = A  + (size_t)(brow + r0) * lda + sl0 * 8;
  const u16* gA1 = A  + (size_t)(brow + r1) * lda + sl0 * 8;
  const u16* gB0 = Bt + (size_t)(bcol + r0) * ldb + sl0 * 8;
  const u16* gB1 = Bt + (size_t)(bcol + r1) * ldb + sl0 * 8;

  const int fr = lane & 15;
  const int ks = lane >> 4;
  const int NT = K >> 5;

#define STAGE(tile, buf)                                          \
  do {                                                            \
    const int kko = (tile) * 32;                                  \
    load_lds16(gA0 + kko, &smA[(buf)][wave * 512]);               \
    load_lds16(gA1 + kko, &smA[(buf)][2048 + wave * 512]);        \
    load_lds16(gB0 + kko, &smB[(buf)][wave * 512]);               \
    load_lds16(gB1 + kko, &smB[(buf)][2048 + wave * 512]);        \
  } while (0)

  // prologue: stage tiles 0 and 1
  STAGE(0, 0);
  STAGE(1, 1);

  for (int tt = 0; tt < NT; ++tt) {
    // tile tt's 4 loads are the oldest; tile tt+1's 4 may still fly
    if (tt == NT - 1) asm volatile("s_waitcnt vmcnt(0)" ::: "memory");
    else              asm volatile("s_waitcnt vmcnt(4)" ::: "memory");
    __builtin_amdgcn_s_barrier();   // all waves: tile tt fully in LDS

    const int cur = tt & 1;
    short8 af[4], bfr[4];
#pragma unroll
    for (int m = 0; m < 4; ++m) {
      const int rA = wr * 64 + m * 16 + fr;
      const int sl = ((rA >> 1) & 3) ^ ks;
      af[m] = *(const short8*)&smA[cur][rA * 32 + sl * 8];
    }
#pragma unroll
    for (int n = 0; n < 4; ++n) {
      const int rB = wc * 64 + n * 16 + fr;
      const int sl = ((rB >> 1) & 3) ^ ks;
      bfr[n] = *(const short8*)&smB[cur][rB * 32 + sl * 8];
    }
    asm volatile("s_waitcnt lgkmcnt(0)" ::: "memory");
    __builtin_amdgcn_s_barrier();   // all waves done reading buf[cur]

    if (tt + 2 < NT) STAGE(tt + 2, cur);  // overwrite the buffer just read

#pragma unroll
    for (int m = 0; m < 4; ++m)
#pragma unroll
      for (int n = 0; n < 4; ++n)
        acc[m][n] = __builtin_amdgcn_mfma_f32_16x16x32_bf16(af[m], bfr[n], acc[m][n], 0, 0, 0);
  }
#undef STAGE

  // ---- epilogue ----
  const int dcol  = lane & 15;
  const int drow0 = (lane >> 4) * 4;
#pragma unroll
  for (int m = 0; m < 4; ++m) {
#pragma unroll
    for (int n = 0; n < 4; ++n) {
      const long col  = bcol + wc * 64 + n * 16 + dcol;
      const long rowb = brow + wr * 64 + m * 16 + drow0;
      float bv = 0.f;
      if (MODE != 2 && bias != nullptr) bv = bias[col];
#pragma unroll
      for (int j = 0; j < 4; ++j) {
        const long row = rowb + j;
        const float val = (acc[m][n][j] + bv) * scale;
        if (MODE == 0)
          ((u16*)Cout)[(long)blockIdx.z * zsC + (size_t)row * ldc + col] = f2bf(val);
        else if (MODE == 1)
          ((u16*)Cout)[(long)blockIdx.z * zsC + (size_t)col * ldc + row] = f2bf(val);
        else
          ((float*)Cout)[(long)blockIdx.z * zsC + (size_t)row * ldc + col] = val;
      }
    }
  }
}

// ---------- fp32 -> bf16 convert (vectorized) ----------
__global__ __launch_bounds__(256)
void cvt_bf16(const float* __restrict__ in, u16* __restrict__ out, int n4)
{
  int i = blockIdx.x * 256 + threadIdx.x;
  const int stride = gridDim.x * 256;
  for (; i < n4; i += stride) {
    const float4 f = ((const float4*)in)[i];
    ushort4 u;
    u.x = f2bf(f.x); u.y = f2bf(f.y); u.z = f2bf(f.z); u.w = f2bf(f.w);
    ((ushort4*)out)[i] = u;
  }
}

// ---------- W[1024,1024] fp32 -> Wt[1024,1024] bf16 (transposed) ----------
__global__ __launch_bounds__(256)
void wtrans(const float* __restrict__ W, u16* __restrict__ Wt)
{
  __shared__ u16 tile[32][33];
  const int tx = threadIdx.x;      // 0..31
  const int ty = threadIdx.y;      // 0..7
  const int bx = blockIdx.x * 32;  // e base
  const int by = blockIdx.y * 32;  // d base
#pragma unroll
  for (int i = 0; i < 4; ++i)
    tile[ty + i * 8][tx] = f2bf(W[(size_t)(by + ty + i * 8) * 1024 + bx + tx]);
  __syncthreads();
#pragma unroll
  for (int i = 0; i < 4; ++i)
    Wt[(size_t)(bx + ty + i * 8) * 1024 + by + tx] = tile[tx][ty + i * 8];
}

// ---------- row softmax, IN-PLACE bf16: S [8192 rows][2048] bf16 ----------
// Each thread reads/writes exactly its own 16 bytes -> no cross-thread race.
__global__ __launch_bounds__(256)
void softmax_rows_bf16(u16* __restrict__ S)
{
  u16* s = S + (size_t)blockIdx.x * 2048;
  const int t = threadIdx.x;

  const short8 r = ((const short8*)s)[t];
  float v[8];
#pragma unroll
  for (int i = 0; i < 8; ++i) v[i] = bf2f((u16)r[i]);

  float m = -1e30f;
#pragma unroll
  for (int i = 0; i < 8; ++i) m = fmaxf(m, v[i]);
#pragma unroll
  for (int o = 32; o; o >>= 1) m = fmaxf(m, __shfl_xor(m, o));
  __shared__ float redm[4], reds[4];
  if ((t & 63) == 0) redm[t >> 6] = m;
  __syncthreads();
  m = fmaxf(fmaxf(redm[0], redm[1]), fmaxf(redm[2], redm[3]));

  float sum = 0.f;
#pragma unroll
  for (int i = 0; i < 8; ++i) { v[i] = __expf(v[i] - m); sum += v[i]; }
#pragma unroll
  for (int o = 32; o; o >>= 1) sum += __shfl_xor(sum, o);
  if ((t & 63) == 0) reds[t >> 6] = sum;
  __syncthreads();
  const float inv = 1.f / (reds[0] + reds[1] + reds[2] + reds[3]);

  short8 w;
#pragma unroll
  for (int i = 0; i < 8; ++i) w[i] = (short)f2bf(v[i] * inv);
  ((short8*)s)[t] = w;
}

// ---------- launch ----------
extern "C" void kernel_launch(void* const* d_in, const int* in_sizes, int n_in,
                              void* d_out, int out_size, void* d_ws, size_t ws_size,
                              hipStream_t stream)
{
  const float* x  = (const float*)d_in[0];
  const float* Wq = (const float*)d_in[1];
  const float* bq = (const float*)d_in[2];
  const float* Wk = (const float*)d_in[3];
  const float* bk = (const float*)d_in[4];
  const float* Wv = (const float*)d_in[5];
  const float* bv = (const float*)d_in[6];
  float* out = (float*)d_out;
  char* ws = (char*)d_ws;

  const size_t MB = (size_t)1 << 20;
  const float qscale = 0.03125f;  // 1/sqrt(1024)
  const long  SO = 2048L * 1024;  // per-batch Q/K/out element stride

  u16* Qb  = (u16*)(ws);             // 16 MB  [8192][1024] bf16, Q pre-scaled
  u16* Kb  = (u16*)(ws + 16 * MB);   // 16 MB
  u16* Vt  = (u16*)(ws + 32 * MB);   // 16 MB  V^T [1024][8192] bf16
  u16* Sc  = (u16*)(ws + 48 * MB);   // 32 MB  scores bf16 [4][2048][2048], P in-place
  u16* xb  = (u16*)(ws + 48 * MB);   // 16 MB  (overlaps Sc; dead before scores)
  u16* Wqt = (u16*)(ws + 80 * MB);   // 2 MB
  u16* Wkt = (u16*)(ws + 82 * MB);
  u16* Wvt = (u16*)(ws + 84 * MB);

  cvt_bf16<<<2048, 256, 0, stream>>>(x, xb, (4 * 2048 * 1024) / 4);
  dim3 tb(32, 8), tg(32, 32);
  wtrans<<<tg, tb, 0, stream>>>(Wq, Wqt);
  wtrans<<<tg, tb, 0, stream>>>(Wk, Wkt);
  wtrans<<<tg, tb, 0, stream>>>(Wv, Wvt);

  // projections: M=8192, N=1024, K=1024
  gemm_bt<0><<<dim3(8, 64), 256, 0, stream>>>(xb, Wqt, Qb, bq, 1024, 1024, 1024, 1024, qscale, 0, 0, 0);
  gemm_bt<0><<<dim3(8, 64), 256, 0, stream>>>(xb, Wkt, Kb, bk, 1024, 1024, 1024, 1024, 1.0f, 0, 0, 0);
  gemm_bt<1><<<dim3(8, 64), 256, 0, stream>>>(xb, Wvt, Vt, bv, 1024, 1024, 1024, 8192, 1.0f, 0, 0, 0);

  // scores (all batches), bf16 out: S_b = Q_b @ K_b^T
  gemm_bt<0><<<dim3(16, 16, 4), 256, 0, stream>>>(Qb, Kb, Sc, nullptr,
      1024, 1024, 1024, 2048, 1.0f, SO, SO, 2048L * 2048);
  softmax_rows_bf16<<<4 * 2048, 256, 0, stream>>>(Sc);
  // out (all batches): P_b @ V_b  (P bf16 in-place in Sc, lda=2048)
  gemm_bt<2><<<dim3(8, 16, 4), 256, 0, stream>>>(Sc, Vt, out, nullptr,
      2048, 2048, 8192, 1024, 1.0f, 2048L * 2048, 2048, SO);
}

// Round 4
// 189.438 us; speedup vs baseline: 2.2139x; 1.1354x over previous
//
#include <hip/hip_runtime.h>

typedef unsigned short u16;
typedef __attribute__((ext_vector_type(8))) short short8;
typedef __attribute__((ext_vector_type(4))) float f32x4;

// ---------- helpers ----------

__device__ __forceinline__ u16 f2bf(float f) {
  union { float f; unsigned u; } c; c.f = f;
  unsigned u = c.u;
  unsigned r = u + 0x7fffu + ((u >> 16) & 1u);
  return (u16)(r >> 16);
}

__device__ __forceinline__ float bf2f(u16 b) {
  union { unsigned u; float f; } c; c.u = ((unsigned)b) << 16;
  return c.f;
}

__device__ __forceinline__ void load_lds16(const void* g, void* l) {
  // dest: wave-uniform base + lane*16 (HW); src: per-lane global address
  __builtin_amdgcn_global_load_lds(
      (__attribute__((address_space(1))) void*)(__UINTPTR_TYPE__)(g),
      (__attribute__((address_space(3))) void*)(l),
      16, 0, 0);
}

template <int N> __device__ __forceinline__ void vm_wait() {
  if constexpr (N == 0) asm volatile("s_waitcnt vmcnt(0)" ::: "memory");
  else if constexpr (N == 3) asm volatile("s_waitcnt vmcnt(3)" ::: "memory");
  else if constexpr (N == 4) asm volatile("s_waitcnt vmcnt(4)" ::: "memory");
}

// ---------- 8-phase 256-wide GEMM: C = A[M,K] @ Bt[N,K]^T ----------
// BM x 256 tile, BK=64, 8 waves (2Mx4N), 512 threads, double-buffered LDS.
// Per K-tile: 4 phases, quadrant (ks, mh). Stage lead = 1 K-tile, 1 K-slice
// half-tile staged per phase into the non-read buffer. vmcnt(LA+2) at phase
// 2 and 4 closes only (counted; no full drain in main loop).
// MODE 0: fused QKV epilogue (C0 = Q base, K at +8192*1024; C1 = Vt transposed)
// MODE 1: bf16 out,  C0[row*ldc+col] = acc*scale
// MODE 2: fp32 out,  C0[row*ldc+col] = acc
template <int BM, int MODE>
__global__ __launch_bounds__(512)
void gemm256(const u16* __restrict__ A, const u16* __restrict__ Bt,
             void* __restrict__ C0, void* __restrict__ C1,
             const float* __restrict__ b0, const float* __restrict__ b1,
             const float* __restrict__ b2,
             int K, int lda, int ldb, int ldc, float scale,
             long zsA, long zsB, long zsC)
{
  constexpr int MREP = BM / 32;        // 8 (BM=256) or 4 (BM=128)
  constexpr int H    = MREP / 2;       // MFMA rows per phase
  constexpr int LA   = BM / 128;       // gloads per A half-tile per thread
  constexpr int BOFF = BM * 64;        // u16 offset of B planes (2 A planes)
  constexpr int LDSE = BM * 64 + 16384;
  __shared__ __align__(16) u16 lds[2][LDSE];

  A  += (long)blockIdx.z * zsA;
  Bt += (long)blockIdx.z * zsB;

  const int t    = threadIdx.x;
  const int lane = t & 63;
  const int wave = t >> 6;
  const int wr   = wave >> 2;          // 0..1
  const int wc   = wave & 3;           // 0..3
  const long brow = (long)blockIdx.y * BM;
  const long bcol = (long)blockIdx.x * 256;

  f32x4 acc[MREP][4];
#pragma unroll
  for (int m = 0; m < MREP; ++m)
#pragma unroll
    for (int n = 0; n < 4; ++n)
#pragma unroll
      for (int j = 0; j < 4; ++j) acc[m][n][j] = 0.f;

  // ---- fragment read addressing (swizzle: slot ^= (row>>1)&3; row-invariant
  // across m/n since 16-row steps don't change (row>>1)&3) ----
  const int frA  = wr * (BM / 2) + (lane & 15);
  const int kAsw = (((lane >> 4) ^ ((frA >> 1) & 3)) * 8);
  const int frB  = wc * 64 + (lane & 15);
  const int kBsw = (((lane >> 4) ^ ((frB >> 1) & 3)) * 8);

  // ---- staging addressing: unit = one K-slice plane (rows x 32 cols) ----
  const int sr  = t >> 2;                              // 0..127
  const int ssl = ((t & 3) ^ ((sr >> 1) & 3)) * 8;     // pre-swizzled source slot
  const u16* gA = A  + (size_t)(brow + sr) * lda + ssl;
  const u16* gB = Bt + (size_t)(bcol + sr) * ldb + ssl;
  const int NT = K >> 6;

#define STAGE_A(nb, kt1, ks) do {                                   \
    u16* d = &lds[(nb)][(ks) * (BM * 32) + t * 8];                  \
    const u16* g = gA + (size_t)(kt1) * 64 + (ks) * 32;             \
    load_lds16(g, d);                                               \
    if (LA == 2) load_lds16(g + (size_t)128 * lda, d + 4096);       \
  } while (0)

#define STAGE_B(nb, kt1, ks) do {                                   \
    u16* d = &lds[(nb)][BOFF + (ks) * 8192 + t * 8];                \
    const u16* g = gB + (size_t)(kt1) * 64 + (ks) * 32;             \
    load_lds16(g, d);                                               \
    load_lds16(g + (size_t)128 * ldb, d + 4096);                    \
  } while (0)

#define PHASE(ks, mh, STG, VM) {                                                 \
    _Pragma("unroll")                                                            \
    for (int i = 0; i < H; ++i)                                                  \
      af[i] = *(const short8*)&bufA[(ks) * (BM * 32) +                           \
                 (size_t)(frA + ((mh) * H + i) * 16) * 32 + kAsw];               \
    if ((mh) == 0) {                                                             \
      _Pragma("unroll")                                                          \
      for (int n = 0; n < 4; ++n)                                                \
        bf[n] = *(const short8*)&bufB[(ks) * 8192 +                              \
                   (size_t)(frB + n * 16) * 32 + kBsw];                          \
    }                                                                            \
    STG;                                                                         \
    asm volatile("s_barrier" ::: "memory");                                      \
    asm volatile("s_waitcnt lgkmcnt(0)" ::: "memory");                           \
    __builtin_amdgcn_sched_barrier(0);                                           \
    __builtin_amdgcn_s_setprio(1);                                               \
    _Pragma("unroll")                                                            \
    for (int i = 0; i < H; ++i)                                                  \
      _Pragma("unroll")                                                          \
      for (int n = 0; n < 4; ++n)                                                \
        acc[(mh) * H + i][n] = __builtin_amdgcn_mfma_f32_16x16x32_bf16(          \
            af[i], bf[n], acc[(mh) * H + i][n], 0, 0, 0);                        \
    __builtin_amdgcn_s_setprio(0);                                               \
    VM;                                                                          \
    asm volatile("s_barrier" ::: "memory");                                      \
  }

  // prologue: stage K-tile 0 fully, drain once
  STAGE_A(0, 0, 0); STAGE_B(0, 0, 0); STAGE_A(0, 0, 1); STAGE_B(0, 0, 1);
  vm_wait<0>();
  asm volatile("s_barrier" ::: "memory");

  short8 af[H], bf[4];
  for (int kt = 0; kt < NT - 1; ++kt) {
    const u16* bufA = &lds[kt & 1][0];
    const u16* bufB = bufA + BOFF;
    const int nb = (kt + 1) & 1;
    PHASE(0, 0, STAGE_A(nb, kt + 1, 0), (void)0)
    PHASE(0, 1, STAGE_B(nb, kt + 1, 0), vm_wait<LA + 2>())
    PHASE(1, 0, STAGE_A(nb, kt + 1, 1), (void)0)
    PHASE(1, 1, STAGE_B(nb, kt + 1, 1), vm_wait<LA + 2>())
  }
  { // peeled final window: no staging; drain remaining before ks1 reads
    const u16* bufA = &lds[(NT - 1) & 1][0];
    const u16* bufB = bufA + BOFF;
    PHASE(0, 0, (void)0, (void)0)
    PHASE(0, 1, (void)0, vm_wait<0>())
    PHASE(1, 0, (void)0, (void)0)
    PHASE(1, 1, (void)0, (void)0)
  }
#undef PHASE
#undef STAGE_A
#undef STAGE_B

  // ---- epilogue ----
  const int dcol = lane & 15;
  const int dr4  = (lane >> 4) * 4;
#pragma unroll
  for (int m = 0; m < MREP; ++m) {
#pragma unroll
    for (int n = 0; n < 4; ++n) {
      const long col  = bcol + wc * 64 + n * 16 + dcol;
      const long row0 = brow + wr * (BM / 2) + m * 16 + dr4;
      if (MODE == 0) {
        const int which = (int)(bcol >> 10);   // block-uniform: 0=Q 1=K 2=V
        const long cp = col - ((long)which << 10);
        if (which < 2) {
          const float sc = which ? 1.0f : scale;
          const float bias = (which ? b1 : b0)[cp];
          u16* dst = (u16*)C0 + (long)which * (8192L * 1024);
#pragma unroll
          for (int j = 0; j < 4; ++j)
            dst[(row0 + j) * 1024 + cp] = f2bf((acc[m][n][j] + bias) * sc);
        } else {
          const float bias = b2[cp];
          u16* dst = (u16*)C1;
#pragma unroll
          for (int j = 0; j < 4; ++j)
            dst[cp * 8192 + (row0 + j)] = f2bf(acc[m][n][j] + bias);
        }
      } else if (MODE == 1) {
#pragma unroll
        for (int j = 0; j < 4; ++j)
          ((u16*)C0)[(long)blockIdx.z * zsC + (row0 + j) * ldc + col] =
              f2bf(acc[m][n][j] * scale);
      } else {
#pragma unroll
        for (int j = 0; j < 4; ++j)
          ((float*)C0)[(long)blockIdx.z * zsC + (row0 + j) * ldc + col] =
              acc[m][n][j];
      }
    }
  }
}

// ---------- fp32 -> bf16 convert (vectorized) ----------
__global__ __launch_bounds__(256)
void cvt_bf16(const float* __restrict__ in, u16* __restrict__ out, int n4)
{
  int i = blockIdx.x * 256 + threadIdx.x;
  const int stride = gridDim.x * 256;
  for (; i < n4; i += stride) {
    const float4 f = ((const float4*)in)[i];
    ushort4 u;
    u.x = f2bf(f.x); u.y = f2bf(f.y); u.z = f2bf(f.z); u.w = f2bf(f.w);
    ((ushort4*)out)[i] = u;
  }
}

// ---------- W[1024,1024] fp32 -> Wt[1024,1024] bf16 (transposed) ----------
__global__ __launch_bounds__(256)
void wtrans(const float* __restrict__ W, u16* __restrict__ Wt)
{
  __shared__ u16 tile[32][33];
  const int tx = threadIdx.x;      // 0..31
  const int ty = threadIdx.y;      // 0..7
  const int bx = blockIdx.x * 32;  // e base
  const int by = blockIdx.y * 32;  // d base
#pragma unroll
  for (int i = 0; i < 4; ++i)
    tile[ty + i * 8][tx] = f2bf(W[(size_t)(by + ty + i * 8) * 1024 + bx + tx]);
  __syncthreads();
#pragma unroll
  for (int i = 0; i < 4; ++i)
    Wt[(size_t)(bx + ty + i * 8) * 1024 + by + tx] = tile[tx][ty + i * 8];
}

// ---------- row softmax, IN-PLACE bf16: S [8192 rows][2048] bf16 ----------
__global__ __launch_bounds__(256)
void softmax_rows_bf16(u16* __restrict__ S)
{
  u16* s = S + (size_t)blockIdx.x * 2048;
  const int t = threadIdx.x;

  const short8 r = ((const short8*)s)[t];
  float v[8];
#pragma unroll
  for (int i = 0; i < 8; ++i) v[i] = bf2f((u16)r[i]);

  float m = -1e30f;
#pragma unroll
  for (int i = 0; i < 8; ++i) m = fmaxf(m, v[i]);
#pragma unroll
  for (int o = 32; o; o >>= 1) m = fmaxf(m, __shfl_xor(m, o));
  __shared__ float redm[4], reds[4];
  if ((t & 63) == 0) redm[t >> 6] = m;
  __syncthreads();
  m = fmaxf(fmaxf(redm[0], redm[1]), fmaxf(redm[2], redm[3]));

  float sum = 0.f;
#pragma unroll
  for (int i = 0; i < 8; ++i) { v[i] = __expf(v[i] - m); sum += v[i]; }
#pragma unroll
  for (int o = 32; o; o >>= 1) sum += __shfl_xor(sum, o);
  if ((t & 63) == 0) reds[t >> 6] = sum;
  __syncthreads();
  const float inv = 1.f / (reds[0] + reds[1] + reds[2] + reds[3]);

  short8 w;
#pragma unroll
  for (int i = 0; i < 8; ++i) w[i] = (short)f2bf(v[i] * inv);
  ((short8*)s)[t] = w;
}

// ---------- launch ----------
extern "C" void kernel_launch(void* const* d_in, const int* in_sizes, int n_in,
                              void* d_out, int out_size, void* d_ws, size_t ws_size,
                              hipStream_t stream)
{
  const float* x  = (const float*)d_in[0];
  const float* Wq = (const float*)d_in[1];
  const float* bq = (const float*)d_in[2];
  const float* Wk = (const float*)d_in[3];
  const float* bk = (const float*)d_in[4];
  const float* Wv = (const float*)d_in[5];
  const float* bv = (const float*)d_in[6];
  float* out = (float*)d_out;
  char* ws = (char*)d_ws;

  const size_t MB = (size_t)1 << 20;
  const float qscale = 0.03125f;   // 1/sqrt(1024)
  const long  SO = 2048L * 1024;   // per-batch Q/K/out element stride

  u16* Qb   = (u16*)(ws);            // 16 MB [8192][1024] bf16 (Q pre-scaled)
  u16* Kb   = (u16*)(ws + 16 * MB);  // 16 MB (must be Qb + 8192*1024!)
  u16* Vt   = (u16*)(ws + 32 * MB);  // 16 MB V^T [1024][8192] bf16
  u16* Sc   = (u16*)(ws + 48 * MB);  // 32 MB scores bf16 [4][2048][2048], P in-place
  u16* xb   = (u16*)(ws + 48 * MB);  // 16 MB (overlaps Sc; dead before scores)
  u16* Wcat = (u16*)(ws + 80 * MB);  // 6 MB  [Wq^T;Wk^T;Wv^T] bf16 [3072][1024]

  cvt_bf16<<<2048, 256, 0, stream>>>(x, xb, (4 * 2048 * 1024) / 4);
  dim3 tb(32, 8), tg(32, 32);
  wtrans<<<tg, tb, 0, stream>>>(Wq, Wcat);
  wtrans<<<tg, tb, 0, stream>>>(Wk, Wcat + 1024 * 1024);
  wtrans<<<tg, tb, 0, stream>>>(Wv, Wcat + 2 * 1024 * 1024);

  // fused QKV projection: [8192,1024] @ [3072,1024]^T, epilogue scatters Q/K/Vt
  gemm256<256, 0><<<dim3(12, 32), 512, 0, stream>>>(
      xb, Wcat, Qb, Vt, bq, bk, bv, 1024, 1024, 1024, 1024, qscale, 0, 0, 0);

  // scores (all batches), bf16 out: S_b = Q_b @ K_b^T
  gemm256<256, 1><<<dim3(8, 8, 4), 512, 0, stream>>>(
      Qb, Kb, Sc, nullptr, nullptr, nullptr, nullptr,
      1024, 1024, 1024, 2048, 1.0f, SO, SO, 2048L * 2048);

  softmax_rows_bf16<<<4 * 2048, 256, 0, stream>>>(Sc);

  // out (all batches): P_b @ V_b  (P bf16 in Sc, lda=2048; Bt = Vt cols b*2048)
  gemm256<128, 2><<<dim3(4, 16, 4), 512, 0, stream>>>(
      Sc, Vt, out, nullptr, nullptr, nullptr, nullptr,
      2048, 2048, 8192, 1024, 1.0f, 2048L * 2048, 2048, SO);
}

// Round 5
// 177.345 us; speedup vs baseline: 2.3648x; 1.0682x over previous
//
#include <hip/hip_runtime.h>

typedef unsigned short u16;
typedef __attribute__((ext_vector_type(8))) short short8;
typedef __attribute__((ext_vector_type(4))) short short4v;
typedef __attribute__((ext_vector_type(4))) float f32x4;

// ---------- helpers ----------

__device__ __forceinline__ u16 f2bf(float f) {
  union { float f; unsigned u; } c; c.f = f;
  unsigned u = c.u;
  unsigned r = u + 0x7fffu + ((u >> 16) & 1u);
  return (u16)(r >> 16);
}

__device__ __forceinline__ float bf2f(u16 b) {
  union { unsigned u; float f; } c; c.u = ((unsigned)b) << 16;
  return c.f;
}

__device__ __forceinline__ void load_lds16(const void* g, void* l) {
  // dest: wave-uniform base + lane*16 (HW); src: per-lane global address
  __builtin_amdgcn_global_load_lds(
      (__attribute__((address_space(1))) void*)(__UINTPTR_TYPE__)(g),
      (__attribute__((address_space(3))) void*)(l),
      16, 0, 0);
}

template <int N> __device__ __forceinline__ void vm_wait() {
  if constexpr (N == 0) asm volatile("s_waitcnt vmcnt(0)" ::: "memory");
  else if constexpr (N == 3) asm volatile("s_waitcnt vmcnt(3)" ::: "memory");
  else if constexpr (N == 4) asm volatile("s_waitcnt vmcnt(4)" ::: "memory");
}

// ---------- 8-phase 256-wide GEMM: C = A[M,K] @ Bt[N,K]^T ----------
// BM x 256 tile, BK=64, 8 waves (2Mx4N), 512 threads, double-buffered LDS.
// Per K-tile: 4 phases, quadrant (ks, mh). Stage lead = 1 K-tile, 1 K-slice
// half-tile staged per phase into the non-read buffer. vmcnt(LA+2) at phase
// 2 and 4 closes only (counted; no full drain in main loop).
// MODE 0: fused QKV epilogue (C0 = Q base, K at +8192*1024; C1 = Vt transposed
//         via LDS round-trip for coalesced writes)
// MODE 1: bf16 out,  C0[row*ldc+col] = acc*scale
// MODE 2: fp32 out,  C0[row*ldc+col] = acc
template <int BM, int MODE>
__global__ __launch_bounds__(512)
void gemm256(const u16* __restrict__ A, const u16* __restrict__ Bt,
             void* __restrict__ C0, void* __restrict__ C1,
             const float* __restrict__ b0, const float* __restrict__ b1,
             const float* __restrict__ b2,
             int K, int lda, int ldb, int ldc, float scale,
             long zsA, long zsB, long zsC)
{
  constexpr int MREP = BM / 32;        // 8 (BM=256) or 4 (BM=128)
  constexpr int H    = MREP / 2;       // MFMA rows per phase
  constexpr int LA   = BM / 128;       // gloads per A half-tile per thread
  constexpr int BOFF = BM * 64;        // u16 offset of B planes (2 A planes)
  constexpr int LDSE = BM * 64 + 16384;
  __shared__ __align__(16) u16 lds[2][LDSE];

  A  += (long)blockIdx.z * zsA;
  Bt += (long)blockIdx.z * zsB;

  const int t    = threadIdx.x;
  const int lane = t & 63;
  const int wave = t >> 6;
  const int wr   = wave >> 2;          // 0..1
  const int wc   = wave & 3;           // 0..3
  const long brow = (long)blockIdx.y * BM;
  const long bcol = (long)blockIdx.x * 256;

  f32x4 acc[MREP][4];
#pragma unroll
  for (int m = 0; m < MREP; ++m)
#pragma unroll
    for (int n = 0; n < 4; ++n)
#pragma unroll
      for (int j = 0; j < 4; ++j) acc[m][n][j] = 0.f;

  // ---- fragment read addressing (swizzle: slot ^= (row>>1)&3; row-invariant
  // across m/n since 16-row steps don't change (row>>1)&3) ----
  const int frA  = wr * (BM / 2) + (lane & 15);
  const int kAsw = (((lane >> 4) ^ ((frA >> 1) & 3)) * 8);
  const int frB  = wc * 64 + (lane & 15);
  const int kBsw = (((lane >> 4) ^ ((frB >> 1) & 3)) * 8);

  // ---- staging addressing: unit = one K-slice plane (rows x 32 cols) ----
  const int sr  = t >> 2;                              // 0..127
  const int ssl = ((t & 3) ^ ((sr >> 1) & 3)) * 8;     // pre-swizzled source slot
  const u16* gA = A  + (size_t)(brow + sr) * lda + ssl;
  const u16* gB = Bt + (size_t)(bcol + sr) * ldb + ssl;
  const int NT = K >> 6;

#define STAGE_A(nb, kt1, ks) do {                                   \
    u16* d = &lds[(nb)][(ks) * (BM * 32) + t * 8];                  \
    const u16* g = gA + (size_t)(kt1) * 64 + (ks) * 32;             \
    load_lds16(g, d);                                               \
    if (LA == 2) load_lds16(g + (size_t)128 * lda, d + 4096);       \
  } while (0)

#define STAGE_B(nb, kt1, ks) do {                                   \
    u16* d = &lds[(nb)][BOFF + (ks) * 8192 + t * 8];                \
    const u16* g = gB + (size_t)(kt1) * 64 + (ks) * 32;             \
    load_lds16(g, d);                                               \
    load_lds16(g + (size_t)128 * ldb, d + 4096);                    \
  } while (0)

#define PHASE(ks, mh, STG, VM) {                                                 \
    _Pragma("unroll")                                                            \
    for (int i = 0; i < H; ++i)                                                  \
      af[i] = *(const short8*)&bufA[(ks) * (BM * 32) +                           \
                 (size_t)(frA + ((mh) * H + i) * 16) * 32 + kAsw];               \
    if ((mh) == 0) {                                                             \
      _Pragma("unroll")                                                          \
      for (int n = 0; n < 4; ++n)                                                \
        bf[n] = *(const short8*)&bufB[(ks) * 8192 +                              \
                   (size_t)(frB + n * 16) * 32 + kBsw];                          \
    }                                                                            \
    STG;                                                                         \
    asm volatile("s_barrier" ::: "memory");                                      \
    asm volatile("s_waitcnt lgkmcnt(0)" ::: "memory");                           \
    __builtin_amdgcn_sched_barrier(0);                                           \
    __builtin_amdgcn_s_setprio(1);                                               \
    _Pragma("unroll")                                                            \
    for (int i = 0; i < H; ++i)                                                  \
      _Pragma("unroll")                                                          \
      for (int n = 0; n < 4; ++n)                                                \
        acc[(mh) * H + i][n] = __builtin_amdgcn_mfma_f32_16x16x32_bf16(          \
            af[i], bf[n], acc[(mh) * H + i][n], 0, 0, 0);                        \
    __builtin_amdgcn_s_setprio(0);                                               \
    VM;                                                                          \
    asm volatile("s_barrier" ::: "memory");                                      \
  }

  // prologue: stage K-tile 0 fully, drain once
  STAGE_A(0, 0, 0); STAGE_B(0, 0, 0); STAGE_A(0, 0, 1); STAGE_B(0, 0, 1);
  vm_wait<0>();
  asm volatile("s_barrier" ::: "memory");

  short8 af[H], bf[4];
  for (int kt = 0; kt < NT - 1; ++kt) {
    const u16* bufA = &lds[kt & 1][0];
    const u16* bufB = bufA + BOFF;
    const int nb = (kt + 1) & 1;
    PHASE(0, 0, STAGE_A(nb, kt + 1, 0), (void)0)
    PHASE(0, 1, STAGE_B(nb, kt + 1, 0), vm_wait<LA + 2>())
    PHASE(1, 0, STAGE_A(nb, kt + 1, 1), (void)0)
    PHASE(1, 1, STAGE_B(nb, kt + 1, 1), vm_wait<LA + 2>())
  }
  { // peeled final window: no staging; drain remaining before ks1 reads
    const u16* bufA = &lds[(NT - 1) & 1][0];
    const u16* bufB = bufA + BOFF;
    PHASE(0, 0, (void)0, (void)0)
    PHASE(0, 1, (void)0, vm_wait<0>())
    PHASE(1, 0, (void)0, (void)0)
    PHASE(1, 1, (void)0, (void)0)
  }
#undef PHASE
#undef STAGE_A
#undef STAGE_B

  // ---- epilogue ----
  const int dcol = lane & 15;
  const int dr4  = (lane >> 4) * 4;
  if (MODE == 0) {
    const int which = (int)(bcol >> 10);   // block-uniform: 0=Q 1=K 2=V
    if (which < 2) {
      const float sc = which ? 1.0f : scale;
      const float* bb = which ? b1 : b0;
      u16* dst = (u16*)C0 + (long)which * (8192L * 1024);
#pragma unroll
      for (int m = 0; m < MREP; ++m) {
#pragma unroll
        for (int n = 0; n < 4; ++n) {
          const long cp   = (bcol - ((long)which << 10)) + wc * 64 + n * 16 + dcol;
          const long row0 = brow + wr * (BM / 2) + m * 16 + dr4;
          const float bias = bb[cp];
#pragma unroll
          for (int j = 0; j < 4; ++j)
            dst[(row0 + j) * 1024 + cp] = f2bf((acc[m][n][j] + bias) * sc);
        }
      }
    } else {
      // V: transpose through LDS (post-pipeline LDS is dead), coalesced out.
      // LDS tile: [cpl 256][rows 256] u16, row-slot (row>>2) XOR cpl&63.
      u16* sm = (u16*)lds;   // 256*256*2B = 128 KB, exactly the LDS block
#pragma unroll
      for (int m = 0; m < MREP; ++m) {
#pragma unroll
        for (int n = 0; n < 4; ++n) {
          const int cpl = wc * 64 + n * 16 + dcol;
          const int r0l = wr * (BM / 2) + m * 16 + dr4;   // multiple of 4
          const float bias = b2[(bcol - 2048) + cpl];
          short4v w;
#pragma unroll
          for (int j = 0; j < 4; ++j) w[j] = (short)f2bf(acc[m][n][j] + bias);
          *(short4v*)&sm[cpl * 256 + (((r0l >> 2) ^ (cpl & 63)) << 2)] = w;
        }
      }
      __syncthreads();
      const long cp0 = bcol - 2048;
      u16* dst = (u16*)C1;
#pragma unroll
      for (int it = 0; it < 16; ++it) {
        const int idx = it * 512 + t;
        const int i  = idx >> 5;     // cpl 0..255
        const int ch = idx & 31;     // 8-row chunk
        const short4v lo = *(const short4v*)&sm[i * 256 + ((((ch * 2)    ) ^ (i & 63)) << 2)];
        const short4v hi = *(const short4v*)&sm[i * 256 + ((((ch * 2) + 1) ^ (i & 63)) << 2)];
        short8 o;
        o[0] = lo[0]; o[1] = lo[1]; o[2] = lo[2]; o[3] = lo[3];
        o[4] = hi[0]; o[5] = hi[1]; o[6] = hi[2]; o[7] = hi[3];
        *(short8*)&dst[(cp0 + i) * 8192 + brow + ch * 8] = o;
      }
    }
  } else {
#pragma unroll
    for (int m = 0; m < MREP; ++m) {
#pragma unroll
      for (int n = 0; n < 4; ++n) {
        const long col  = bcol + wc * 64 + n * 16 + dcol;
        const long row0 = brow + wr * (BM / 2) + m * 16 + dr4;
        if (MODE == 1) {
#pragma unroll
          for (int j = 0; j < 4; ++j)
            ((u16*)C0)[(long)blockIdx.z * zsC + (row0 + j) * ldc + col] =
                f2bf(acc[m][n][j] * scale);
        } else {
#pragma unroll
          for (int j = 0; j < 4; ++j)
            ((float*)C0)[(long)blockIdx.z * zsC + (row0 + j) * ldc + col] =
                acc[m][n][j];
        }
      }
    }
  }
}

// ---------- fp32 -> bf16 convert (vectorized) ----------
__global__ __launch_bounds__(256)
void cvt_bf16(const float* __restrict__ in, u16* __restrict__ out, int n4)
{
  int i = blockIdx.x * 256 + threadIdx.x;
  const int stride = gridDim.x * 256;
  for (; i < n4; i += stride) {
    const float4 f = ((const float4*)in)[i];
    ushort4 u;
    u.x = f2bf(f.x); u.y = f2bf(f.y); u.z = f2bf(f.z); u.w = f2bf(f.w);
    ((ushort4*)out)[i] = u;
  }
}

// ---------- W[1024,1024] fp32 -> Wt[1024,1024] bf16 (transposed) ----------
__global__ __launch_bounds__(256)
void wtrans(const float* __restrict__ W, u16* __restrict__ Wt)
{
  __shared__ u16 tile[32][33];
  const int tx = threadIdx.x;      // 0..31
  const int ty = threadIdx.y;      // 0..7
  const int bx = blockIdx.x * 32;  // e base
  const int by = blockIdx.y * 32;  // d base
#pragma unroll
  for (int i = 0; i < 4; ++i)
    tile[ty + i * 8][tx] = f2bf(W[(size_t)(by + ty + i * 8) * 1024 + bx + tx]);
  __syncthreads();
#pragma unroll
  for (int i = 0; i < 4; ++i)
    Wt[(size_t)(bx + ty + i * 8) * 1024 + by + tx] = tile[tx][ty + i * 8];
}

// ---------- row softmax, IN-PLACE bf16: S [8192 rows][2048] bf16 ----------
__global__ __launch_bounds__(256)
void softmax_rows_bf16(u16* __restrict__ S)
{
  u16* s = S + (size_t)blockIdx.x * 2048;
  const int t = threadIdx.x;

  const short8 r = ((const short8*)s)[t];
  float v[8];
#pragma unroll
  for (int i = 0; i < 8; ++i) v[i] = bf2f((u16)r[i]);

  float m = -1e30f;
#pragma unroll
  for (int i = 0; i < 8; ++i) m = fmaxf(m, v[i]);
#pragma unroll
  for (int o = 32; o; o >>= 1) m = fmaxf(m, __shfl_xor(m, o));
  __shared__ float redm[4], reds[4];
  if ((t & 63) == 0) redm[t >> 6] = m;
  __syncthreads();
  m = fmaxf(fmaxf(redm[0], redm[1]), fmaxf(redm[2], redm[3]));

  float sum = 0.f;
#pragma unroll
  for (int i = 0; i < 8; ++i) { v[i] = __expf(v[i] - m); sum += v[i]; }
#pragma unroll
  for (int o = 32; o; o >>= 1) sum += __shfl_xor(sum, o);
  if ((t & 63) == 0) reds[t >> 6] = sum;
  __syncthreads();
  const float inv = 1.f / (reds[0] + reds[1] + reds[2] + reds[3]);

  short8 w;
#pragma unroll
  for (int i = 0; i < 8; ++i) w[i] = (short)f2bf(v[i] * inv);
  ((short8*)s)[t] = w;
}

// ---------- launch ----------
extern "C" void kernel_launch(void* const* d_in, const int* in_sizes, int n_in,
                              void* d_out, int out_size, void* d_ws, size_t ws_size,
                              hipStream_t stream)
{
  const float* x  = (const float*)d_in[0];
  const float* Wq = (const float*)d_in[1];
  const float* bq = (const float*)d_in[2];
  const float* Wk = (const float*)d_in[3];
  const float* bk = (const float*)d_in[4];
  const float* Wv = (const float*)d_in[5];
  const float* bv = (const float*)d_in[6];
  float* out = (float*)d_out;
  char* ws = (char*)d_ws;

  const size_t MB = (size_t)1 << 20;
  const float qscale = 0.03125f;   // 1/sqrt(1024)
  const long  SO = 2048L * 1024;   // per-batch Q/K/out element stride

  u16* Qb   = (u16*)(ws);            // 16 MB [8192][1024] bf16 (Q pre-scaled)
  u16* Kb   = (u16*)(ws + 16 * MB);  // 16 MB (must be Qb + 8192*1024!)
  u16* Vt   = (u16*)(ws + 32 * MB);  // 16 MB V^T [1024][8192] bf16
  u16* Sc   = (u16*)(ws + 48 * MB);  // 32 MB scores bf16 [4][2048][2048], P in-place
  u16* xb   = (u16*)(ws + 48 * MB);  // 16 MB (overlaps Sc; dead before scores)
  u16* Wcat = (u16*)(ws + 80 * MB);  // 6 MB  [Wq^T;Wk^T;Wv^T] bf16 [3072][1024]

  cvt_bf16<<<2048, 256, 0, stream>>>(x, xb, (4 * 2048 * 1024) / 4);
  dim3 tb(32, 8), tg(32, 32);
  wtrans<<<tg, tb, 0, stream>>>(Wq, Wcat);
  wtrans<<<tg, tb, 0, stream>>>(Wk, Wcat + 1024 * 1024);
  wtrans<<<tg, tb, 0, stream>>>(Wv, Wcat + 2 * 1024 * 1024);

  // fused QKV projection: [8192,1024] @ [3072,1024]^T, epilogue scatters Q/K/Vt
  gemm256<256, 0><<<dim3(12, 32), 512, 0, stream>>>(
      xb, Wcat, Qb, Vt, bq, bk, bv, 1024, 1024, 1024, 1024, qscale, 0, 0, 0);

  // scores (all batches), bf16 out: S_b = Q_b @ K_b^T
  gemm256<256, 1><<<dim3(8, 8, 4), 512, 0, stream>>>(
      Qb, Kb, Sc, nullptr, nullptr, nullptr, nullptr,
      1024, 1024, 1024, 2048, 1.0f, SO, SO, 2048L * 2048);

  softmax_rows_bf16<<<4 * 2048, 256, 0, stream>>>(Sc);

  // out (all batches): P_b @ V_b  (P bf16 in Sc, lda=2048; Bt = Vt cols b*2048)
  gemm256<128, 2><<<dim3(4, 16, 4), 512, 0, stream>>>(
      Sc, Vt, out, nullptr, nullptr, nullptr, nullptr,
      2048, 2048, 8192, 1024, 1.0f, 2048L * 2048, 2048, SO);
}

// Round 6
// 174.634 us; speedup vs baseline: 2.4015x; 1.0155x over previous
//
#include <hip/hip_runtime.h>

typedef unsigned short u16;
typedef __attribute__((ext_vector_type(8))) short short8;
typedef __attribute__((ext_vector_type(4))) short short4v;
typedef __attribute__((ext_vector_type(4))) float f32x4;

// ---------- helpers ----------

__device__ __forceinline__ u16 f2bf(float f) {
  union { float f; unsigned u; } c; c.f = f;
  unsigned u = c.u;
  unsigned r = u + 0x7fffu + ((u >> 16) & 1u);
  return (u16)(r >> 16);
}

__device__ __forceinline__ float bf2f(u16 b) {
  union { unsigned u; float f; } c; c.u = ((unsigned)b) << 16;
  return c.f;
}

__device__ __forceinline__ void load_lds16(const void* g, void* l) {
  // dest: wave-uniform base + lane*16 (HW); src: per-lane global address
  __builtin_amdgcn_global_load_lds(
      (__attribute__((address_space(1))) void*)(__UINTPTR_TYPE__)(g),
      (__attribute__((address_space(3))) void*)(l),
      16, 0, 0);
}

template <int N> __device__ __forceinline__ void vm_wait() {
  if constexpr (N == 0) asm volatile("s_waitcnt vmcnt(0)" ::: "memory");
  else if constexpr (N == 3) asm volatile("s_waitcnt vmcnt(3)" ::: "memory");
  else if constexpr (N == 4) asm volatile("s_waitcnt vmcnt(4)" ::: "memory");
}

// ---------- 8-phase 256-wide GEMM: C = A[M,K] @ Bt[N,K]^T ----------
// BM x 256 tile, BK=64, 8 waves (2Mx4N), 512 threads, double-buffered LDS.
// 4 phases per K-tile, quadrant (ks, mh). ONE barrier per phase (at end):
// within a phase waves slip, so one wave's ds_reads overlap another's MFMA.
// WAR on the staged buffer is closed by each wave's own lgkmcnt(0) before
// its barrier arrival. vmcnt(LA+2) at phases 2 and 4 only (counted; no full
// drain in the main loop).
// MODE 0: fused QKV epilogue (C0 = Q base, K at +8192*1024; C1 = Vt transposed
//         via LDS round-trip for coalesced writes); XCD-swizzled grid.
// MODE 1: bf16 out,  C0[row*ldc+col] = acc*scale
// MODE 2: fp32 out,  C0[row*ldc+col] = acc
template <int BM, int MODE>
__global__ __launch_bounds__(512)
void gemm256(const u16* __restrict__ A, const u16* __restrict__ Bt,
             void* __restrict__ C0, void* __restrict__ C1,
             const float* __restrict__ b0, const float* __restrict__ b1,
             const float* __restrict__ b2,
             int K, int lda, int ldb, int ldc, float scale,
             long zsA, long zsB, long zsC)
{
  constexpr int MREP = BM / 32;        // 8 (BM=256) or 4 (BM=128)
  constexpr int H    = MREP / 2;       // MFMA rows per phase
  constexpr int LA   = BM / 128;       // gloads per A half-tile per thread
  constexpr int BOFF = BM * 64;        // u16 offset of B planes (2 A planes)
  constexpr int LDSE = BM * 64 + 16384;
  __shared__ __align__(16) u16 lds[2][LDSE];

  A  += (long)blockIdx.z * zsA;
  Bt += (long)blockIdx.z * zsB;

  // block coords (XCD-bijective swizzle for the big QKV grid; 384 % 8 == 0)
  int bxi, byi;
  if (MODE == 0) {
    const int orig = blockIdx.x + 12 * blockIdx.y;     // 0..383
    const int s    = (orig & 7) * 48 + (orig >> 3);    // bijective
    bxi = s % 12; byi = s / 12;
  } else {
    bxi = blockIdx.x; byi = blockIdx.y;
  }

  const int t    = threadIdx.x;
  const int lane = t & 63;
  const int wave = t >> 6;
  const int wr   = wave >> 2;          // 0..1
  const int wc   = wave & 3;           // 0..3
  const long brow = (long)byi * BM;
  const long bcol = (long)bxi * 256;

  f32x4 acc[MREP][4];
#pragma unroll
  for (int m = 0; m < MREP; ++m)
#pragma unroll
    for (int n = 0; n < 4; ++n)
#pragma unroll
      for (int j = 0; j < 4; ++j) acc[m][n][j] = 0.f;

  // ---- fragment read addressing (swizzle: slot ^= (row>>1)&3; row-invariant
  // across m/n since 16-row steps don't change (row>>1)&3) ----
  const int frA  = wr * (BM / 2) + (lane & 15);
  const int kAsw = (((lane >> 4) ^ ((frA >> 1) & 3)) * 8);
  const int frB  = wc * 64 + (lane & 15);
  const int kBsw = (((lane >> 4) ^ ((frB >> 1) & 3)) * 8);

  // ---- staging addressing: unit = one K-slice plane (rows x 32 cols) ----
  const int sr  = t >> 2;                              // 0..127
  const int ssl = ((t & 3) ^ ((sr >> 1) & 3)) * 8;     // pre-swizzled source slot
  const u16* gA = A  + (size_t)(brow + sr) * lda + ssl;
  const u16* gB = Bt + (size_t)(bcol + sr) * ldb + ssl;
  const int NT = K >> 6;

#define STAGE_A(nb, kt1, ks) do {                                   \
    u16* d = &lds[(nb)][(ks) * (BM * 32) + t * 8];                  \
    const u16* g = gA + (size_t)(kt1) * 64 + (ks) * 32;             \
    load_lds16(g, d);                                               \
    if (LA == 2) load_lds16(g + (size_t)128 * lda, d + 4096);       \
  } while (0)

#define STAGE_B(nb, kt1, ks) do {                                   \
    u16* d = &lds[(nb)][BOFF + (ks) * 8192 + t * 8];                \
    const u16* g = gB + (size_t)(kt1) * 64 + (ks) * 32;             \
    load_lds16(g, d);                                               \
    load_lds16(g + (size_t)128 * ldb, d + 4096);                    \
  } while (0)

// ONE barrier per phase: reads+stage issue, own-lgkm drain, MFMA, counted VM,
// then the phase-end barrier (publishes staged data AND closes the WAR window).
#define PHASE(ks, mh, STG, VM) {                                                 \
    _Pragma("unroll")                                                            \
    for (int i = 0; i < H; ++i)                                                  \
      af[i] = *(const short8*)&bufA[(ks) * (BM * 32) +                           \
                 (size_t)(frA + ((mh) * H + i) * 16) * 32 + kAsw];               \
    if ((mh) == 0) {                                                             \
      _Pragma("unroll")                                                          \
      for (int n = 0; n < 4; ++n)                                                \
        bf[n] = *(const short8*)&bufB[(ks) * 8192 +                              \
                   (size_t)(frB + n * 16) * 32 + kBsw];                          \
    }                                                                            \
    STG;                                                                         \
    asm volatile("s_waitcnt lgkmcnt(0)" ::: "memory");                           \
    __builtin_amdgcn_sched_barrier(0);                                           \
    __builtin_amdgcn_s_setprio(1);                                               \
    _Pragma("unroll")                                                            \
    for (int i = 0; i < H; ++i)                                                  \
      _Pragma("unroll")                                                          \
      for (int n = 0; n < 4; ++n)                                                \
        acc[(mh) * H + i][n] = __builtin_amdgcn_mfma_f32_16x16x32_bf16(          \
            af[i], bf[n], acc[(mh) * H + i][n], 0, 0, 0);                        \
    __builtin_amdgcn_s_setprio(0);                                               \
    VM;                                                                          \
    asm volatile("s_barrier" ::: "memory");                                      \
  }

  // prologue: stage K-tile 0 fully, drain once
  STAGE_A(0, 0, 0); STAGE_B(0, 0, 0); STAGE_A(0, 0, 1); STAGE_B(0, 0, 1);
  vm_wait<0>();
  asm volatile("s_barrier" ::: "memory");

  short8 af[H], bf[4];
  for (int kt = 0; kt < NT - 1; ++kt) {
    const u16* bufA = &lds[kt & 1][0];
    const u16* bufB = bufA + BOFF;
    const int nb = (kt + 1) & 1;
    PHASE(0, 0, STAGE_A(nb, kt + 1, 0), (void)0)
    PHASE(0, 1, STAGE_B(nb, kt + 1, 0), vm_wait<LA + 2>())
    PHASE(1, 0, STAGE_A(nb, kt + 1, 1), (void)0)
    PHASE(1, 1, STAGE_B(nb, kt + 1, 1), vm_wait<LA + 2>())
  }
  { // peeled final window: no staging; drain remaining before ks1 reads
    const u16* bufA = &lds[(NT - 1) & 1][0];
    const u16* bufB = bufA + BOFF;
    PHASE(0, 0, (void)0, (void)0)
    PHASE(0, 1, (void)0, vm_wait<0>())
    PHASE(1, 0, (void)0, (void)0)
    PHASE(1, 1, (void)0, (void)0)
  }
#undef PHASE
#undef STAGE_A
#undef STAGE_B

  // ---- epilogue ----
  const int dcol = lane & 15;
  const int dr4  = (lane >> 4) * 4;
  if (MODE == 0) {
    const int which = (int)(bcol >> 10);   // block-uniform: 0=Q 1=K 2=V
    if (which < 2) {
      const float sc = which ? 1.0f : scale;
      const float* bb = which ? b1 : b0;
      u16* dst = (u16*)C0 + (long)which * (8192L * 1024);
#pragma unroll
      for (int m = 0; m < MREP; ++m) {
#pragma unroll
        for (int n = 0; n < 4; ++n) {
          const long cp   = (bcol - ((long)which << 10)) + wc * 64 + n * 16 + dcol;
          const long row0 = brow + wr * (BM / 2) + m * 16 + dr4;
          const float bias = bb[cp];
#pragma unroll
          for (int j = 0; j < 4; ++j)
            dst[(row0 + j) * 1024 + cp] = f2bf((acc[m][n][j] + bias) * sc);
        }
      }
    } else {
      // V: transpose through LDS (post-pipeline LDS is dead), coalesced out.
      // LDS tile: [cpl 256][rows 256] u16, row-slot (row>>2) XOR cpl&63.
      u16* sm = (u16*)lds;   // 256*256*2B = 128 KB, exactly the LDS block
#pragma unroll
      for (int m = 0; m < MREP; ++m) {
#pragma unroll
        for (int n = 0; n < 4; ++n) {
          const int cpl = wc * 64 + n * 16 + dcol;
          const int r0l = wr * (BM / 2) + m * 16 + dr4;   // multiple of 4
          const float bias = b2[(bcol - 2048) + cpl];
          short4v w;
#pragma unroll
          for (int j = 0; j < 4; ++j) w[j] = (short)f2bf(acc[m][n][j] + bias);
          *(short4v*)&sm[cpl * 256 + (((r0l >> 2) ^ (cpl & 63)) << 2)] = w;
        }
      }
      __syncthreads();
      const long cp0 = bcol - 2048;
      u16* dst = (u16*)C1;
#pragma unroll
      for (int it = 0; it < 16; ++it) {
        const int idx = it * 512 + t;
        const int i  = idx >> 5;     // cpl 0..255
        const int ch = idx & 31;     // 8-row chunk
        const short4v lo = *(const short4v*)&sm[i * 256 + ((((ch * 2)    ) ^ (i & 63)) << 2)];
        const short4v hi = *(const short4v*)&sm[i * 256 + ((((ch * 2) + 1) ^ (i & 63)) << 2)];
        short8 o;
        o[0] = lo[0]; o[1] = lo[1]; o[2] = lo[2]; o[3] = lo[3];
        o[4] = hi[0]; o[5] = hi[1]; o[6] = hi[2]; o[7] = hi[3];
        *(short8*)&dst[(cp0 + i) * 8192 + brow + ch * 8] = o;
      }
    }
  } else {
#pragma unroll
    for (int m = 0; m < MREP; ++m) {
#pragma unroll
      for (int n = 0; n < 4; ++n) {
        const long col  = bcol + wc * 64 + n * 16 + dcol;
        const long row0 = brow + wr * (BM / 2) + m * 16 + dr4;
        if (MODE == 1) {
#pragma unroll
          for (int j = 0; j < 4; ++j)
            ((u16*)C0)[(long)blockIdx.z * zsC + (row0 + j) * ldc + col] =
                f2bf(acc[m][n][j] * scale);
        } else {
#pragma unroll
          for (int j = 0; j < 4; ++j)
            ((float*)C0)[(long)blockIdx.z * zsC + (row0 + j) * ldc + col] =
                acc[m][n][j];
        }
      }
    }
  }
}

// ---------- fp32 -> bf16 convert (vectorized) ----------
__global__ __launch_bounds__(256)
void cvt_bf16(const float* __restrict__ in, u16* __restrict__ out, int n4)
{
  int i = blockIdx.x * 256 + threadIdx.x;
  const int stride = gridDim.x * 256;
  for (; i < n4; i += stride) {
    const float4 f = ((const float4*)in)[i];
    ushort4 u;
    u.x = f2bf(f.x); u.y = f2bf(f.y); u.z = f2bf(f.z); u.w = f2bf(f.w);
    ((ushort4*)out)[i] = u;
  }
}

// ---------- W[1024,1024] fp32 -> Wt[1024,1024] bf16 (transposed) ----------
__global__ __launch_bounds__(256)
void wtrans(const float* __restrict__ W, u16* __restrict__ Wt)
{
  __shared__ u16 tile[32][33];
  const int tx = threadIdx.x;      // 0..31
  const int ty = threadIdx.y;      // 0..7
  const int bx = blockIdx.x * 32;  // e base
  const int by = blockIdx.y * 32;  // d base
#pragma unroll
  for (int i = 0; i < 4; ++i)
    tile[ty + i * 8][tx] = f2bf(W[(size_t)(by + ty + i * 8) * 1024 + bx + tx]);
  __syncthreads();
#pragma unroll
  for (int i = 0; i < 4; ++i)
    Wt[(size_t)(bx + ty + i * 8) * 1024 + by + tx] = tile[tx][ty + i * 8];
}

// ---------- row softmax, IN-PLACE bf16: S [8192 rows][2048] bf16 ----------
__global__ __launch_bounds__(256)
void softmax_rows_bf16(u16* __restrict__ S)
{
  u16* s = S + (size_t)blockIdx.x * 2048;
  const int t = threadIdx.x;

  const short8 r = ((const short8*)s)[t];
  float v[8];
#pragma unroll
  for (int i = 0; i < 8; ++i) v[i] = bf2f((u16)r[i]);

  float m = -1e30f;
#pragma unroll
  for (int i = 0; i < 8; ++i) m = fmaxf(m, v[i]);
#pragma unroll
  for (int o = 32; o; o >>= 1) m = fmaxf(m, __shfl_xor(m, o));
  __shared__ float redm[4], reds[4];
  if ((t & 63) == 0) redm[t >> 6] = m;
  __syncthreads();
  m = fmaxf(fmaxf(redm[0], redm[1]), fmaxf(redm[2], redm[3]));

  float sum = 0.f;
#pragma unroll
  for (int i = 0; i < 8; ++i) { v[i] = __expf(v[i] - m); sum += v[i]; }
#pragma unroll
  for (int o = 32; o; o >>= 1) sum += __shfl_xor(sum, o);
  if ((t & 63) == 0) reds[t >> 6] = sum;
  __syncthreads();
  const float inv = 1.f / (reds[0] + reds[1] + reds[2] + reds[3]);

  short8 w;
#pragma unroll
  for (int i = 0; i < 8; ++i) w[i] = (short)f2bf(v[i] * inv);
  ((short8*)s)[t] = w;
}

// ---------- launch ----------
extern "C" void kernel_launch(void* const* d_in, const int* in_sizes, int n_in,
                              void* d_out, int out_size, void* d_ws, size_t ws_size,
                              hipStream_t stream)
{
  const float* x  = (const float*)d_in[0];
  const float* Wq = (const float*)d_in[1];
  const float* bq = (const float*)d_in[2];
  const float* Wk = (const float*)d_in[3];
  const float* bk = (const float*)d_in[4];
  const float* Wv = (const float*)d_in[5];
  const float* bv = (const float*)d_in[6];
  float* out = (float*)d_out;
  char* ws = (char*)d_ws;

  const size_t MB = (size_t)1 << 20;
  const float qscale = 0.03125f;   // 1/sqrt(1024)
  const long  SO = 2048L * 1024;   // per-batch Q/K/out element stride

  u16* Qb   = (u16*)(ws);            // 16 MB [8192][1024] bf16 (Q pre-scaled)
  u16* Kb   = (u16*)(ws + 16 * MB);  // 16 MB (must be Qb + 8192*1024!)
  u16* Vt   = (u16*)(ws + 32 * MB);  // 16 MB V^T [1024][8192] bf16
  u16* Sc   = (u16*)(ws + 48 * MB);  // 32 MB scores bf16 [4][2048][2048], P in-place
  u16* xb   = (u16*)(ws + 48 * MB);  // 16 MB (overlaps Sc; dead before scores)
  u16* Wcat = (u16*)(ws + 80 * MB);  // 6 MB  [Wq^T;Wk^T;Wv^T] bf16 [3072][1024]

  cvt_bf16<<<2048, 256, 0, stream>>>(x, xb, (4 * 2048 * 1024) / 4);
  dim3 tb(32, 8), tg(32, 32);
  wtrans<<<tg, tb, 0, stream>>>(Wq, Wcat);
  wtrans<<<tg, tb, 0, stream>>>(Wk, Wcat + 1024 * 1024);
  wtrans<<<tg, tb, 0, stream>>>(Wv, Wcat + 2 * 1024 * 1024);

  // fused QKV projection: [8192,1024] @ [3072,1024]^T, epilogue scatters Q/K/Vt
  gemm256<256, 0><<<dim3(12, 32), 512, 0, stream>>>(
      xb, Wcat, Qb, Vt, bq, bk, bv, 1024, 1024, 1024, 1024, qscale, 0, 0, 0);

  // scores (all batches), bf16 out: S_b = Q_b @ K_b^T
  gemm256<256, 1><<<dim3(8, 8, 4), 512, 0, stream>>>(
      Qb, Kb, Sc, nullptr, nullptr, nullptr, nullptr,
      1024, 1024, 1024, 2048, 1.0f, SO, SO, 2048L * 2048);

  softmax_rows_bf16<<<4 * 2048, 256, 0, stream>>>(Sc);

  // out (all batches): P_b @ V_b  (P bf16 in Sc, lda=2048; Bt = Vt cols b*2048)
  gemm256<128, 2><<<dim3(4, 16, 4), 512, 0, stream>>>(
      Sc, Vt, out, nullptr, nullptr, nullptr, nullptr,
      2048, 2048, 8192, 1024, 1.0f, 2048L * 2048, 2048, SO);
}

// Round 7
// 173.977 us; speedup vs baseline: 2.4106x; 1.0038x over previous
//
#include <hip/hip_runtime.h>

typedef unsigned short u16;
typedef __attribute__((ext_vector_type(8))) short short8;
typedef __attribute__((ext_vector_type(4))) short short4v;
typedef __attribute__((ext_vector_type(4))) float f32x4;

// ---------- helpers ----------

__device__ __forceinline__ u16 f2bf(float f) {
  union { float f; unsigned u; } c; c.f = f;
  unsigned u = c.u;
  unsigned r = u + 0x7fffu + ((u >> 16) & 1u);
  return (u16)(r >> 16);
}

__device__ __forceinline__ float bf2f(u16 b) {
  union { unsigned u; float f; } c; c.u = ((unsigned)b) << 16;
  return c.f;
}

__device__ __forceinline__ void load_lds16(const void* g, void* l) {
  // dest: wave-uniform base + lane*16 (HW); src: per-lane global address
  __builtin_amdgcn_global_load_lds(
      (__attribute__((address_space(1))) void*)(__UINTPTR_TYPE__)(g),
      (__attribute__((address_space(3))) void*)(l),
      16, 0, 0);
}

template <int N> __device__ __forceinline__ void vm_wait() {
  if constexpr (N == 0) asm volatile("s_waitcnt vmcnt(0)" ::: "memory");
  else if constexpr (N == 3) asm volatile("s_waitcnt vmcnt(3)" ::: "memory");
  else if constexpr (N == 4) asm volatile("s_waitcnt vmcnt(4)" ::: "memory");
}

// ---------- 8-phase 256-wide GEMM: C = A[M,K] @ Bt[N,K]^T ----------
// BM x 256 tile, BK=64, 8 waves (2Mx4N), 512 threads, double-buffered LDS.
// 4 phases per K-tile, quadrant (ks, mh). ONE barrier per phase (at end).
// vmcnt(LA+2) at phases 2 and 4 only (counted; no full drain in main loop).
// MODE 0: QK fused epilogue (C0 = Q base, K at +8192*1024), bias+scale, XCD swz
// MODE 1: bf16 out,  C0[row*ldc+col] = acc*scale
// MODE 2: fp32 out,  C0[row*ldc+col] = acc
// MODE 3: V epilogue: C1 = Vt[1024][8192] via LDS-transpose, bias b2, XCD swz
template <int BM, int MODE>
__global__ __launch_bounds__(512)
void gemm256(const u16* __restrict__ A, const u16* __restrict__ Bt,
             void* __restrict__ C0, void* __restrict__ C1,
             const float* __restrict__ b0, const float* __restrict__ b1,
             const float* __restrict__ b2,
             int K, int lda, int ldb, int ldc, float scale,
             long zsA, long zsB, long zsC)
{
  constexpr int MREP = BM / 32;        // 8 (BM=256) or 4 (BM=128)
  constexpr int H    = MREP / 2;       // MFMA rows per phase
  constexpr int LA   = BM / 128;       // gloads per A half-tile per thread
  constexpr int BOFF = BM * 64;        // u16 offset of B planes (2 A planes)
  constexpr int LDSE = BM * 64 + 16384;
  __shared__ __align__(16) u16 lds[2][LDSE];

  A  += (long)blockIdx.z * zsA;
  Bt += (long)blockIdx.z * zsB;

  // block coords; bijective XCD swizzle for the full-machine 256-block grids
  int bxi, byi;
  if (MODE == 0 || MODE == 3) {
    const int gw   = gridDim.x;
    const int nwg  = gw * gridDim.y;                   // 256 (multiple of 8)
    const int orig = blockIdx.x + gw * blockIdx.y;
    const int s    = (orig & 7) * (nwg >> 3) + (orig >> 3);
    bxi = s % gw; byi = s / gw;
  } else {
    bxi = blockIdx.x; byi = blockIdx.y;
  }

  const int t    = threadIdx.x;
  const int lane = t & 63;
  const int wave = t >> 6;
  const int wr   = wave >> 2;          // 0..1
  const int wc   = wave & 3;           // 0..3
  const long brow = (long)byi * BM;
  const long bcol = (long)bxi * 256;

  f32x4 acc[MREP][4];
#pragma unroll
  for (int m = 0; m < MREP; ++m)
#pragma unroll
    for (int n = 0; n < 4; ++n)
#pragma unroll
      for (int j = 0; j < 4; ++j) acc[m][n][j] = 0.f;

  // ---- fragment read addressing (swizzle: slot ^= (row>>1)&3; row-invariant
  // across m/n since 16-row steps don't change (row>>1)&3) ----
  const int frA  = wr * (BM / 2) + (lane & 15);
  const int kAsw = (((lane >> 4) ^ ((frA >> 1) & 3)) * 8);
  const int frB  = wc * 64 + (lane & 15);
  const int kBsw = (((lane >> 4) ^ ((frB >> 1) & 3)) * 8);

  // ---- staging addressing: unit = one K-slice plane (rows x 32 cols) ----
  const int sr  = t >> 2;                              // 0..127
  const int ssl = ((t & 3) ^ ((sr >> 1) & 3)) * 8;     // pre-swizzled source slot
  const u16* gA = A  + (size_t)(brow + sr) * lda + ssl;
  const u16* gB = Bt + (size_t)(bcol + sr) * ldb + ssl;
  const int NT = K >> 6;

#define STAGE_A(nb, kt1, ks) do {                                   \
    u16* d = &lds[(nb)][(ks) * (BM * 32) + t * 8];                  \
    const u16* g = gA + (size_t)(kt1) * 64 + (ks) * 32;             \
    load_lds16(g, d);                                               \
    if (LA == 2) load_lds16(g + (size_t)128 * lda, d + 4096);       \
  } while (0)

#define STAGE_B(nb, kt1, ks) do {                                   \
    u16* d = &lds[(nb)][BOFF + (ks) * 8192 + t * 8];                \
    const u16* g = gB + (size_t)(kt1) * 64 + (ks) * 32;             \
    load_lds16(g, d);                                               \
    load_lds16(g + (size_t)128 * ldb, d + 4096);                    \
  } while (0)

// ONE barrier per phase: reads+stage issue, own-lgkm drain, MFMA, counted VM,
// then the phase-end barrier (publishes staged data AND closes the WAR window).
#define PHASE(ks, mh, STG, VM) {                                                 \
    _Pragma("unroll")                                                            \
    for (int i = 0; i < H; ++i)                                                  \
      af[i] = *(const short8*)&bufA[(ks) * (BM * 32) +                           \
                 (size_t)(frA + ((mh) * H + i) * 16) * 32 + kAsw];               \
    if ((mh) == 0) {                                                             \
      _Pragma("unroll")                                                          \
      for (int n = 0; n < 4; ++n)                                                \
        bf[n] = *(const short8*)&bufB[(ks) * 8192 +                              \
                   (size_t)(frB + n * 16) * 32 + kBsw];                          \
    }                                                                            \
    STG;                                                                         \
    asm volatile("s_waitcnt lgkmcnt(0)" ::: "memory");                           \
    __builtin_amdgcn_sched_barrier(0);                                           \
    __builtin_amdgcn_s_setprio(1);                                               \
    _Pragma("unroll")                                                            \
    for (int i = 0; i < H; ++i)                                                  \
      _Pragma("unroll")                                                          \
      for (int n = 0; n < 4; ++n)                                                \
        acc[(mh) * H + i][n] = __builtin_amdgcn_mfma_f32_16x16x32_bf16(          \
            af[i], bf[n], acc[(mh) * H + i][n], 0, 0, 0);                        \
    __builtin_amdgcn_s_setprio(0);                                               \
    VM;                                                                          \
    asm volatile("s_barrier" ::: "memory");                                      \
  }

  // prologue: stage K-tile 0 fully, drain once
  STAGE_A(0, 0, 0); STAGE_B(0, 0, 0); STAGE_A(0, 0, 1); STAGE_B(0, 0, 1);
  vm_wait<0>();
  asm volatile("s_barrier" ::: "memory");

  short8 af[H], bf[4];
  for (int kt = 0; kt < NT - 1; ++kt) {
    const u16* bufA = &lds[kt & 1][0];
    const u16* bufB = bufA + BOFF;
    const int nb = (kt + 1) & 1;
    PHASE(0, 0, STAGE_A(nb, kt + 1, 0), (void)0)
    PHASE(0, 1, STAGE_B(nb, kt + 1, 0), vm_wait<LA + 2>())
    PHASE(1, 0, STAGE_A(nb, kt + 1, 1), (void)0)
    PHASE(1, 1, STAGE_B(nb, kt + 1, 1), vm_wait<LA + 2>())
  }
  { // peeled final window: no staging; drain remaining before ks1 reads
    const u16* bufA = &lds[(NT - 1) & 1][0];
    const u16* bufB = bufA + BOFF;
    PHASE(0, 0, (void)0, (void)0)
    PHASE(0, 1, (void)0, vm_wait<0>())
    PHASE(1, 0, (void)0, (void)0)
    PHASE(1, 1, (void)0, (void)0)
  }
#undef PHASE
#undef STAGE_A
#undef STAGE_B

  // ---- epilogue ----
  const int dcol = lane & 15;
  const int dr4  = (lane >> 4) * 4;
  if (MODE == 0) {
    // QK: which = 0 -> Q (scaled), 1 -> K. Block-uniform.
    const int which = (int)(bcol >> 10);
    const float sc = which ? 1.0f : scale;
    const float* bb = which ? b1 : b0;
    u16* dst = (u16*)C0 + (long)which * (8192L * 1024);
#pragma unroll
    for (int m = 0; m < MREP; ++m) {
#pragma unroll
      for (int n = 0; n < 4; ++n) {
        const long cp   = (bcol - ((long)which << 10)) + wc * 64 + n * 16 + dcol;
        const long row0 = brow + wr * (BM / 2) + m * 16 + dr4;
        const float bias = bb[cp];
#pragma unroll
        for (int j = 0; j < 4; ++j)
          dst[(row0 + j) * 1024 + cp] = f2bf((acc[m][n][j] + bias) * sc);
      }
    }
  } else if (MODE == 3) {
    // V: transpose through LDS (post-pipeline LDS is dead), coalesced out.
    // LDS tile: [cpl 256][rows BM] u16, 4-row slot XOR cpl&(BM/4-1).
    constexpr int SMSK = BM / 4 - 1;     // 31 for BM=128
    u16* sm = (u16*)lds;                 // 256*BM*2 bytes (64 KB for BM=128)
#pragma unroll
    for (int m = 0; m < MREP; ++m) {
#pragma unroll
      for (int n = 0; n < 4; ++n) {
        const int cpl = wc * 64 + n * 16 + dcol;
        const int r0l = wr * (BM / 2) + m * 16 + dr4;   // multiple of 4
        const float bias = b2[bcol + cpl];
        short4v w;
#pragma unroll
        for (int j = 0; j < 4; ++j) w[j] = (short)f2bf(acc[m][n][j] + bias);
        *(short4v*)&sm[cpl * BM + (((r0l >> 2) ^ (cpl & SMSK)) << 2)] = w;
      }
    }
    __syncthreads();
    u16* dst = (u16*)C1;
#pragma unroll
    for (int it = 0; it < BM / 16; ++it) {
      const int idx = it * 512 + t;
      const int i  = idx / (BM / 8);     // cpl 0..255
      const int ch = idx & (BM / 8 - 1); // 8-row chunk
      const short4v lo = *(const short4v*)&sm[i * BM + ((((ch * 2)    ) ^ (i & SMSK)) << 2)];
      const short4v hi = *(const short4v*)&sm[i * BM + ((((ch * 2) + 1) ^ (i & SMSK)) << 2)];
      short8 o;
      o[0] = lo[0]; o[1] = lo[1]; o[2] = lo[2]; o[3] = lo[3];
      o[4] = hi[0]; o[5] = hi[1]; o[6] = hi[2]; o[7] = hi[3];
      *(short8*)&dst[(bcol + i) * 8192 + brow + ch * 8] = o;
    }
  } else {
#pragma unroll
    for (int m = 0; m < MREP; ++m) {
#pragma unroll
      for (int n = 0; n < 4; ++n) {
        const long col  = bcol + wc * 64 + n * 16 + dcol;
        const long row0 = brow + wr * (BM / 2) + m * 16 + dr4;
        if (MODE == 1) {
#pragma unroll
          for (int j = 0; j < 4; ++j)
            ((u16*)C0)[(long)blockIdx.z * zsC + (row0 + j) * ldc + col] =
                f2bf(acc[m][n][j] * scale);
        } else {
#pragma unroll
          for (int j = 0; j < 4; ++j)
            ((float*)C0)[(long)blockIdx.z * zsC + (row0 + j) * ldc + col] =
                acc[m][n][j];
        }
      }
    }
  }
}

// ---------- fp32 -> bf16 convert (vectorized) ----------
__global__ __launch_bounds__(256)
void cvt_bf16(const float* __restrict__ in, u16* __restrict__ out, int n4)
{
  int i = blockIdx.x * 256 + threadIdx.x;
  const int stride = gridDim.x * 256;
  for (; i < n4; i += stride) {
    const float4 f = ((const float4*)in)[i];
    ushort4 u;
    u.x = f2bf(f.x); u.y = f2bf(f.y); u.z = f2bf(f.z); u.w = f2bf(f.w);
    ((ushort4*)out)[i] = u;
  }
}

// ---------- W[1024,1024] fp32 -> Wt[1024,1024] bf16 (transposed) ----------
__global__ __launch_bounds__(256)
void wtrans(const float* __restrict__ W, u16* __restrict__ Wt)
{
  __shared__ u16 tile[32][33];
  const int tx = threadIdx.x;      // 0..31
  const int ty = threadIdx.y;      // 0..7
  const int bx = blockIdx.x * 32;  // e base
  const int by = blockIdx.y * 32;  // d base
#pragma unroll
  for (int i = 0; i < 4; ++i)
    tile[ty + i * 8][tx] = f2bf(W[(size_t)(by + ty + i * 8) * 1024 + bx + tx]);
  __syncthreads();
#pragma unroll
  for (int i = 0; i < 4; ++i)
    Wt[(size_t)(bx + ty + i * 8) * 1024 + by + tx] = tile[tx][ty + i * 8];
}

// ---------- row softmax, IN-PLACE bf16: S [8192 rows][2048] bf16 ----------
__global__ __launch_bounds__(256)
void softmax_rows_bf16(u16* __restrict__ S)
{
  u16* s = S + (size_t)blockIdx.x * 2048;
  const int t = threadIdx.x;

  const short8 r = ((const short8*)s)[t];
  float v[8];
#pragma unroll
  for (int i = 0; i < 8; ++i) v[i] = bf2f((u16)r[i]);

  float m = -1e30f;
#pragma unroll
  for (int i = 0; i < 8; ++i) m = fmaxf(m, v[i]);
#pragma unroll
  for (int o = 32; o; o >>= 1) m = fmaxf(m, __shfl_xor(m, o));
  __shared__ float redm[4], reds[4];
  if ((t & 63) == 0) redm[t >> 6] = m;
  __syncthreads();
  m = fmaxf(fmaxf(redm[0], redm[1]), fmaxf(redm[2], redm[3]));

  float sum = 0.f;
#pragma unroll
  for (int i = 0; i < 8; ++i) { v[i] = __expf(v[i] - m); sum += v[i]; }
#pragma unroll
  for (int o = 32; o; o >>= 1) sum += __shfl_xor(sum, o);
  if ((t & 63) == 0) reds[t >> 6] = sum;
  __syncthreads();
  const float inv = 1.f / (reds[0] + reds[1] + reds[2] + reds[3]);

  short8 w;
#pragma unroll
  for (int i = 0; i < 8; ++i) w[i] = (short)f2bf(v[i] * inv);
  ((short8*)s)[t] = w;
}

// ---------- launch ----------
extern "C" void kernel_launch(void* const* d_in, const int* in_sizes, int n_in,
                              void* d_out, int out_size, void* d_ws, size_t ws_size,
                              hipStream_t stream)
{
  const float* x  = (const float*)d_in[0];
  const float* Wq = (const float*)d_in[1];
  const float* bq = (const float*)d_in[2];
  const float* Wk = (const float*)d_in[3];
  const float* bk = (const float*)d_in[4];
  const float* Wv = (const float*)d_in[5];
  const float* bv = (const float*)d_in[6];
  float* out = (float*)d_out;
  char* ws = (char*)d_ws;

  const size_t MB = (size_t)1 << 20;
  const float qscale = 0.03125f;   // 1/sqrt(1024)
  const long  SO = 2048L * 1024;   // per-batch Q/K/out element stride

  u16* Qb   = (u16*)(ws);            // 16 MB [8192][1024] bf16 (Q pre-scaled)
  u16* Kb   = (u16*)(ws + 16 * MB);  // 16 MB (must be Qb + 8192*1024!)
  u16* Vt   = (u16*)(ws + 32 * MB);  // 16 MB V^T [1024][8192] bf16
  u16* Sc   = (u16*)(ws + 48 * MB);  // 32 MB scores bf16 [4][2048][2048], P in-place
  u16* xb   = (u16*)(ws + 48 * MB);  // 16 MB (overlaps Sc; dead before scores)
  u16* Wcat = (u16*)(ws + 80 * MB);  // 6 MB  [Wq^T;Wk^T;Wv^T] bf16 [3072][1024]

  cvt_bf16<<<2048, 256, 0, stream>>>(x, xb, (4 * 2048 * 1024) / 4);
  dim3 tb(32, 8), tg(32, 32);
  wtrans<<<tg, tb, 0, stream>>>(Wq, Wcat);
  wtrans<<<tg, tb, 0, stream>>>(Wk, Wcat + 1024 * 1024);
  wtrans<<<tg, tb, 0, stream>>>(Wv, Wcat + 2 * 1024 * 1024);

  // QK projection: [8192,1024] @ [2048,1024]^T -> Q (scaled) and K. 256 blocks.
  gemm256<256, 0><<<dim3(8, 32), 512, 0, stream>>>(
      xb, Wcat, Qb, nullptr, bq, bk, nullptr,
      1024, 1024, 1024, 1024, qscale, 0, 0, 0);

  // V projection: [8192,1024] @ [1024,1024]^T -> Vt transposed. 256 blocks.
  gemm256<128, 3><<<dim3(4, 64), 512, 0, stream>>>(
      xb, Wcat + 2 * 1024 * 1024, nullptr, Vt, nullptr, nullptr, bv,
      1024, 1024, 1024, 1024, 1.0f, 0, 0, 0);

  // scores (all batches), bf16 out: S_b = Q_b @ K_b^T. 256 blocks.
  gemm256<256, 1><<<dim3(8, 8, 4), 512, 0, stream>>>(
      Qb, Kb, Sc, nullptr, nullptr, nullptr, nullptr,
      1024, 1024, 1024, 2048, 1.0f, SO, SO, 2048L * 2048);

  softmax_rows_bf16<<<4 * 2048, 256, 0, stream>>>(Sc);

  // out (all batches): P_b @ V_b  (P bf16 in Sc, lda=2048; Bt = Vt cols b*2048)
  gemm256<128, 2><<<dim3(4, 16, 4), 512, 0, stream>>>(
      Sc, Vt, out, nullptr, nullptr, nullptr, nullptr,
      2048, 2048, 8192, 1024, 1.0f, 2048L * 2048, 2048, SO);
}